// Round 7
// baseline (680.716 us; speedup 1.0000x reference)
//
#include <hip/hip_runtime.h>
#include <hip/hip_bf16.h>
#include <math.h>

// ---------------------------------------------------------------------------
// TransformerBlock fwd: ln1 -> qkv gemm -> causal flash attn -> proj+res
//   -> ln2 -> ffn1(buggy-gelu) -> ffn2+res.  bf16 MFMA, fp32 softmax/LN.
// R7: race-free 8-phase GEMM. Per phase: reads -> stage -> [vmcnt] ->
//   barrier -> lgkmcnt(0) -> MFMA -> barrier.  vmcnt ONLY at ph4/ph8
//   (N=4 for 256x256, N=2 for 128x256) -- each RAW edge is confirmed by a
//   vmcnt->barrier pair >=1 phase before the dependent cross-wave ds_read;
//   WAR edges closed by lgkmcnt(0)+end-barrier before restage.
// ---------------------------------------------------------------------------

typedef short bf16x8 __attribute__((ext_vector_type(8)));
typedef float f32x4 __attribute__((ext_vector_type(4)));
typedef short short4v __attribute__((ext_vector_type(4)));

#define MFMA16x32(a, b, c) __builtin_amdgcn_mfma_f32_16x16x32_bf16((a), (b), (c), 0, 0, 0)

__device__ __forceinline__ short f2bs(float f) {
    unsigned u = __builtin_bit_cast(unsigned, f);
    unsigned r = (u + 0x7FFFu + ((u >> 16) & 1u)) >> 16;
    return (short)(unsigned short)r;
}

__device__ __forceinline__ void gload_lds16(const void* g, void* l) {
    __builtin_amdgcn_global_load_lds(
        (const __attribute__((address_space(1))) unsigned int*)g,
        (__attribute__((address_space(3))) unsigned int*)l, 16, 0, 0);
}

template <int N>
__device__ __forceinline__ void vmw() {
    if constexpr (N == 0) asm volatile("s_waitcnt vmcnt(0)" ::: "memory");
    else if constexpr (N == 2) asm volatile("s_waitcnt vmcnt(2)" ::: "memory");
    else if constexpr (N == 4) asm volatile("s_waitcnt vmcnt(4)" ::: "memory");
}

// ---------- transpose fp32 (R x C) -> bf16 (C x R) ----------
__global__ __launch_bounds__(256) void transpose_kernel(const float* __restrict__ in,
                                                        short* __restrict__ out,
                                                        int R, int C) {
    __shared__ float tile[32][33];
    const int tx = threadIdx.x & 31;
    const int ty = threadIdx.x >> 5;
    const int c0 = blockIdx.x * 32;
    const int r0 = blockIdx.y * 32;
#pragma unroll
    for (int i = 0; i < 4; ++i) {
        int r = ty + i * 8;
        tile[r][tx] = in[(size_t)(r0 + r) * C + c0 + tx];
    }
    __syncthreads();
#pragma unroll
    for (int i = 0; i < 4; ++i) {
        int r = ty + i * 8;
        out[(size_t)(c0 + r) * R + r0 + tx] = f2bs(tile[tx][r]);
    }
}

// ---------- layernorm fp32 row (D=2048) -> bf16 row ----------
__global__ __launch_bounds__(256) void ln_kernel(const float* __restrict__ x,
                                                 const float* __restrict__ sc,
                                                 const float* __restrict__ sh,
                                                 short* __restrict__ out) {
    const int D = 2048;
    const int row = blockIdx.x;
    const int tid = threadIdx.x;
    __shared__ float red[4];
    const float4* xr = (const float4*)(x + (size_t)row * D);
    float4 v0 = xr[tid];
    float4 v1 = xr[tid + 256];
    float vals0[4] = {v0.x, v0.y, v0.z, v0.w};
    float vals1[4] = {v1.x, v1.y, v1.z, v1.w};

    float s = vals0[0] + vals0[1] + vals0[2] + vals0[3] + vals1[0] + vals1[1] + vals1[2] + vals1[3];
#pragma unroll
    for (int off = 32; off; off >>= 1) s += __shfl_xor(s, off);
    if ((tid & 63) == 0) red[tid >> 6] = s;
    __syncthreads();
    float mean = (red[0] + red[1] + red[2] + red[3]) * (1.0f / 2048.0f);
    __syncthreads();

    float q = 0.0f;
#pragma unroll
    for (int j = 0; j < 4; ++j) {
        float t0 = vals0[j] - mean;
        float t1 = vals1[j] - mean;
        q += t0 * t0 + t1 * t1;
    }
#pragma unroll
    for (int off = 32; off; off >>= 1) q += __shfl_xor(q, off);
    if ((tid & 63) == 0) red[tid >> 6] = q;
    __syncthreads();
    float var = (red[0] + red[1] + red[2] + red[3]) * (1.0f / 2048.0f);
    float inv = rsqrtf(var + 1e-5f);

    const int c0 = tid * 4;
    const int c1 = (tid + 256) * 4;
    short4v o0, o1;
#pragma unroll
    for (int j = 0; j < 4; ++j) {
        o0[j] = f2bs(sc[c0 + j] * ((vals0[j] - mean) * inv) + sh[c0 + j]);
        o1[j] = f2bs(sc[c1 + j] * ((vals1[j] - mean) * inv) + sh[c1 + j]);
    }
    *(short4v*)(out + (size_t)row * D + c0) = o0;
    *(short4v*)(out + (size_t)row * D + c1) = o1;
}

// ---------- bf16 GEMM, race-free 8-phase schedule ----------
// C[M,N] = A[M,K] @ Bt[N,K]^T.  BK=64, 512 thr = 8 waves (2M x 4N).
// LDS dbuf=2: [A0|A1|B0|B1]. Tile even->A0/B0 (read ph1-4), odd->A1/B1 (ph5-8).
// Stage calendar: ph1:B1h0(t+1) ph2:B1h1(t+1) ph3:A0h0(t+2) ph4:A0h1(t+2)
//                 ph5:B0h0(t+2) ph6:B0h1(t+2) ph7:A1h0(t+3) ph8:A1h1(t+3)
// vmcnt(V4) at ph4 (confirms through B1h1) and ph8 (through B0h1), each
// followed by a barrier BEFORE any dependent read (next phase or later).
template <int BM, int BN, int EPI>
__global__ __launch_bounds__(512, 2) void gemm8p(const short* __restrict__ Aop,
                                                 const short* __restrict__ Bt,
                                                 int M, int N, int K,
                                                 void* __restrict__ Cout,
                                                 const float* __restrict__ bias,
                                                 const float* __restrict__ res,
                                                 float gconst) {
    constexpr int MF = BM / 32;   // m-frags per wave (2 waves in M)
    constexpr int NF = BN / 64;   // n-frags per wave (4 waves in N)
    constexpr int QM = MF / 2, QN = NF / 2;
    constexpr int ASZ = BM * 64;
    constexpr int BSZ = BN * 64;
    constexpr int V4 = (BM == 256) ? 4 : 2;   // loads staged per 2 phases of A
    extern __shared__ __align__(16) short lds8[];
    short* const A0 = lds8;
    short* const A1 = lds8 + ASZ;
    short* const B0 = lds8 + 2 * ASZ;
    short* const B1 = lds8 + 2 * ASZ + BSZ;

    const int tid = threadIdx.x;
    const int lane = tid & 63;
    const int wid = tid >> 6;
    const int wm = wid >> 2, wn = wid & 3;
    const int l15 = lane & 15, grp = lane >> 4;

    // T1 XCD-bijective remap (grid %8 == 0 for all launches here)
    const int gx = gridDim.x;
    int flat = (int)blockIdx.y * gx + (int)blockIdx.x;
    const int cpx = (gx * (int)gridDim.y) >> 3;
    flat = (flat & 7) * cpx + (flat >> 3);
    const int bx = flat % gx, by = flat / gx;
    const long m0 = (long)by * BM, n0 = (long)bx * BN;

    f32x4 zero = {0.f, 0.f, 0.f, 0.f};
    f32x4 acc[MF][NF];
#pragma unroll
    for (int i = 0; i < MF; i++)
#pragma unroll
        for (int j = 0; j < NF; j++) acc[i][j] = zero;
    bf16x8 af[MF][2], bfr[NF][2];

    auto stA = [&](int t, int half, short* dst) {
        const long k0 = (long)t << 6;
#pragma unroll
        for (int j = 0; j < BM / 128; ++j) {
            int c = tid + j * 512;
            int row = c >> 3, sl = (c & 7) ^ (row & 7);
            gload_lds16(Aop + (size_t)(m0 + half * (BM / 2) + row) * K + k0 + sl * 8,
                        dst + (size_t)half * (BM / 2) * 64 + (size_t)c * 8);
        }
    };
    auto stB = [&](int t, int half, short* dst) {
        const long k0 = (long)t << 6;
#pragma unroll
        for (int j = 0; j < BN / 128; ++j) {
            int c = tid + j * 512;
            int row = c >> 3, sl = (c & 7) ^ (row & 7);
            gload_lds16(Bt + (size_t)(n0 + half * (BN / 2) + row) * K + k0 + sl * 8,
                        dst + (size_t)half * (BN / 2) * 64 + (size_t)c * 8);
        }
    };

#define LOADA(qm_, buf_)                                                      \
    _Pragma("unroll") for (int kk = 0; kk < 2; ++kk)                          \
    _Pragma("unroll") for (int mi = 0; mi < QM; ++mi) {                       \
        const int row = wm * (MF * 16) + ((qm_)*QM + mi) * 16 + l15;          \
        af[(qm_)*QM + mi][kk] = *(const bf16x8*)((buf_) + row * 64 +          \
            (((kk * 4 + grp) ^ (row & 7)) * 8));                              \
    }
#define LOADB(qn_, buf_)                                                      \
    _Pragma("unroll") for (int kk = 0; kk < 2; ++kk)                          \
    _Pragma("unroll") for (int ni = 0; ni < QN; ++ni) {                       \
        const int row = wn * (NF * 16) + ((qn_)*QN + ni) * 16 + l15;          \
        bfr[(qn_)*QN + ni][kk] = *(const bf16x8*)((buf_) + row * 64 +         \
            (((kk * 4 + grp) ^ (row & 7)) * 8));                              \
    }
#define QUADM(qm_, qn_)                                                       \
    _Pragma("unroll") for (int kk = 0; kk < 2; ++kk)                          \
    _Pragma("unroll") for (int mi = 0; mi < QM; ++mi)                         \
    _Pragma("unroll") for (int ni = 0; ni < QN; ++ni)                         \
        acc[(qm_)*QM + mi][(qn_)*QN + ni] =                                   \
            MFMA16x32(af[(qm_)*QM + mi][kk], bfr[(qn_)*QN + ni][kk],          \
                      acc[(qm_)*QM + mi][(qn_)*QN + ni]);
#define PHT(qm_, qn_)                                                         \
    __builtin_amdgcn_sched_barrier(0);                                        \
    __builtin_amdgcn_s_barrier();                                             \
    asm volatile("s_waitcnt lgkmcnt(0)" ::: "memory");                        \
    __builtin_amdgcn_sched_barrier(0);                                        \
    __builtin_amdgcn_s_setprio(1);                                            \
    QUADM(qm_, qn_);                                                          \
    __builtin_amdgcn_s_setprio(0);                                            \
    __builtin_amdgcn_s_barrier();

    const int nt = K >> 6;
    const int nt2 = nt >> 1;
    // prologue: tile0 (A0,B0) + tile1 A (A1); B1 staged in-loop ph1/2.
    stA(0, 0, A0); stA(0, 1, A0); stB(0, 0, B0); stB(0, 1, B0);
    stA(1, 0, A1); stA(1, 1, A1);
    vmw<V4>();   // tile0 confirmed (A1 may still be in flight)
    __builtin_amdgcn_s_barrier();

    for (int i = 0; i < nt2; ++i) {
        const int t = 2 * i;
        const bool haveT2 = (t + 2 < nt);
        const bool haveT3 = (t + 3 < nt);
        // ph1: reads confirmed by prev ph8's vmcnt->barrier
        LOADA(0, A0) LOADB(0, B0)
        stB(t + 1, 0, B1);
        PHT(0, 0)
        // ph2
        LOADA(1, A0)
        stB(t + 1, 1, B1);
        PHT(1, 0)
        // ph3  (A0 reads done by ph2 end-barrier -> restage safe)
        LOADB(1, B0)
        if (haveT2) stA(t + 2, 0, A0);
        PHT(0, 1)
        // ph4: vmcnt confirms through B1h1 (ph2) for ph5+ reads
        if (haveT2) stA(t + 2, 1, A0);
        if (haveT2) { vmw<V4>(); } else { vmw<0>(); }
        PHT(1, 1)
        // ph5  (B0 reads done by ph3 -> restage safe)
        LOADA(0, A1) LOADB(0, B1)
        if (haveT2) stB(t + 2, 0, B0);
        PHT(0, 0)
        // ph6
        LOADA(1, A1)
        if (haveT2) stB(t + 2, 1, B0);
        PHT(1, 0)
        // ph7  (A1 reads done by ph6 -> restage safe)
        LOADB(1, B1)
        if (haveT3) stA(t + 3, 0, A1);
        PHT(0, 1)
        // ph8: vmcnt confirms through B0h1 (ph6) for next ph1 reads
        if (haveT3) stA(t + 3, 1, A1);
        if (haveT2) { vmw<V4>(); }   // last iter: no further reads
        PHT(1, 1)
    }

#pragma unroll
    for (int mi = 0; mi < MF; mi++) {
        long gr = m0 + wm * (MF * 16) + mi * 16 + grp * 4;
#pragma unroll
        for (int ni = 0; ni < NF; ni++) {
            long gcol = n0 + wn * (NF * 16) + ni * 16 + l15;
#pragma unroll
            for (int r = 0; r < 4; r++) {
                float vv = acc[mi][ni][r];
                long idx = (gr + r) * N + gcol;
                if (EPI == 0) {
                    ((short*)Cout)[idx] = f2bs(vv);
                } else if (EPI == 1) {
                    ((float*)Cout)[idx] = vv + bias[gcol] + res[idx];
                } else {
                    float tv = vv + bias[gcol];
                    float g = 0.5f * tv * (1.0f + gconst * (tv + 0.044715f * tv * tv * tv));
                    ((short*)Cout)[idx] = f2bs(g);
                }
            }
        }
    }
#undef LOADA
#undef LOADB
#undef QUADM
#undef PHT
}

// ---------- reshape: qkv[4096,6144] K-cols -> Kh[32][2048][128] ----------
__global__ __launch_bounds__(256) void reshape_k_kernel(const short* __restrict__ qkv,
                                                        short* __restrict__ Kh) {
    size_t idx = ((size_t)blockIdx.x * 256 + threadIdx.x) * 8;
    int d = (int)(idx & 127);
    int s = (int)((idx >> 7) & 2047);
    int bh = (int)(idx >> 18);
    int b = bh >> 4, h = bh & 15;
    const short* src = qkv + (size_t)(b * 2048 + s) * 6144 + 2048 + h * 128 + d;
    *(bf16x8*)(Kh + idx) = *(const bf16x8*)src;
}

// ---------- reshape: qkv V-cols -> Vt[32][128][2048] (transposed) ----------
__global__ __launch_bounds__(256) void reshape_v_kernel(const short* __restrict__ qkv,
                                                        short* __restrict__ Vt) {
    __shared__ short tile[32][33];
    const int bid = blockIdx.x;
    const int dt = bid & 3, st = (bid >> 2) & 63, bh = bid >> 8;
    const int b = bh >> 4, h = bh & 15;
    const int s0 = st * 32, d0 = dt * 32;
    const int tx = threadIdx.x & 31, ty = threadIdx.x >> 5;
#pragma unroll
    for (int i = 0; i < 4; ++i) {
        int s = ty + i * 8;
        tile[s][tx] = qkv[(size_t)(b * 2048 + s0 + s) * 6144 + 4096 + h * 128 + d0 + tx];
    }
    __syncthreads();
#pragma unroll
    for (int i = 0; i < 4; ++i) {
        int d = ty + i * 8;
        Vt[((size_t)bh * 128 + d0 + d) * 2048 + s0 + tx] = tile[tx][d];
    }
}

// ---------- causal flash attention, paired q-tiles + double-buffered K/V ----
__global__ __launch_bounds__(256) void flash3_kernel(const short* __restrict__ qp,  // qkv, ld 6144
                                                     const short* __restrict__ Kh,  // [32][2048][128]
                                                     const short* __restrict__ Vt,  // [32][128][2048]
                                                     short* __restrict__ ctx) {
    const int S = 2048, D = 2048, HD = 128, LD = 6144;
    __shared__ __align__(16) short Ks[2][64 * 128];
    __shared__ __align__(16) short Vs[2][64 * 128];
    __shared__ __align__(16) short Ps[4][16 * 64];
    const int tid = threadIdx.x;
    const int lane = tid & 63, wid = tid >> 6;
    const int l15 = lane & 15, grp = lane >> 4;

    int bid = (int)blockIdx.x;
    bid = (bid & 7) * 64 + (bid >> 3);
    const int p = bid & 15, bh = bid >> 4;
    const int b = bh >> 4, h = bh & 15;
    const int qtH = 31 - p;
    const int nH = qtH + 1;
    const float scale = 0.08838834764831845f;
    const float NEGINF = -__builtin_inff();

    const short* Kbase = Kh + (size_t)bh * S * 128;
    const short* Vbase = Vt + (size_t)bh * 128 * S;
    short* Psw = &Ps[wid][0];

    f32x4 zero = {0.f, 0.f, 0.f, 0.f};
    bf16x8 aq[4];
    float m_[4], l_[4];
    f32x4 o[8];

    int qt = qtH;
    int qw = qt * 64 + wid * 16;
    {
        const short* qrow = qp + (size_t)(b * S + qw + l15) * LD + h * HD;
#pragma unroll
        for (int kc = 0; kc < 4; kc++) aq[kc] = *(const bf16x8*)(qrow + kc * 32 + grp * 8);
    }
#pragma unroll
    for (int r = 0; r < 4; r++) { m_[r] = NEGINF; l_[r] = 0.f; }
#pragma unroll
    for (int n = 0; n < 8; n++) o[n] = zero;

#pragma unroll
    for (int j = 0; j < 4; ++j) {
        int c = tid + j * 256;
        int r = c >> 4, sl = c & 15;
        gload_lds16(Kbase + (size_t)r * 128 + ((sl ^ (r & 7)) * 8),
                    Ks[0] + (size_t)(wid * 64 + j * 256) * 8);
    }
#pragma unroll
    for (int j = 0; j < 4; ++j) {
        int c = tid + j * 256;
        int d = c >> 3, sl = c & 7;
        gload_lds16(Vbase + (size_t)d * S + ((sl ^ (d & 7)) * 8),
                    Vs[0] + (size_t)(wid * 64 + j * 256) * 8);
    }
    __syncthreads();

    int cur = 0;
    for (int i = 0; i < 33; ++i) {
        const int kt = (i < nH) ? i : (i - nH);
        const bool lastT = (kt == qt);

        if (i + 1 < 33) {
            const int ktn = (i + 1 < nH) ? (i + 1) : (i + 1 - nH);
            const long kn0 = (long)ktn * 64;
            const short* Kg = Kbase + kn0 * 128;
            const short* Vg = Vbase + kn0;
            short* kd = Ks[cur ^ 1];
            short* vd = Vs[cur ^ 1];
#pragma unroll
            for (int j = 0; j < 4; ++j) {
                int c = tid + j * 256;
                int r = c >> 4, sl = c & 15;
                gload_lds16(Kg + (size_t)r * 128 + ((sl ^ (r & 7)) * 8),
                            kd + (size_t)(wid * 64 + j * 256) * 8);
            }
#pragma unroll
            for (int j = 0; j < 4; ++j) {
                int c = tid + j * 256;
                int d = c >> 3, sl = c & 7;
                gload_lds16(Vg + (size_t)d * S + ((sl ^ (d & 7)) * 8),
                            vd + (size_t)(wid * 64 + j * 256) * 8);
            }
        }

        const short* Kc = Ks[cur];
        const short* Vc = Vs[cur];

        f32x4 s[4] = {zero, zero, zero, zero};
#pragma unroll
        for (int n = 0; n < 4; ++n) {
            int r = n * 16 + l15;
#pragma unroll
            for (int kc = 0; kc < 4; ++kc) {
                bf16x8 kb = *(const bf16x8*)(Kc + r * 128 + (((kc * 4 + grp) ^ (r & 7)) * 8));
                s[n] = MFMA16x32(aq[kc], kb, s[n]);
            }
        }

        float al[4];
#pragma unroll
        for (int r = 0; r < 4; ++r) {
            float v[4];
#pragma unroll
            for (int n = 0; n < 4; ++n) v[n] = s[n][r] * scale;
            if (lastT) {
                int qrel = wid * 16 + grp * 4 + r;
#pragma unroll
                for (int n = 0; n < 4; ++n)
                    if (n * 16 + l15 > qrel) v[n] = NEGINF;
            }
            float mx = fmaxf(fmaxf(v[0], v[1]), fmaxf(v[2], v[3]));
            mx = fmaxf(mx, __shfl_xor(mx, 1));
            mx = fmaxf(mx, __shfl_xor(mx, 2));
            mx = fmaxf(mx, __shfl_xor(mx, 4));
            mx = fmaxf(mx, __shfl_xor(mx, 8));
            float mn = fmaxf(m_[r], mx);
            float sc_ = __expf(m_[r] - mn);
            float rs = 0.f;
            int q = grp * 4 + r;
#pragma unroll
            for (int n = 0; n < 4; ++n) {
                v[n] = __expf(v[n] - mn);
                rs += v[n];
                Psw[q * 64 + (((n * 2 + (l15 >> 3)) ^ (q & 7)) * 8) + (l15 & 7)] = f2bs(v[n]);
            }
            rs += __shfl_xor(rs, 1);
            rs += __shfl_xor(rs, 2);
            rs += __shfl_xor(rs, 4);
            rs += __shfl_xor(rs, 8);
            l_[r] = l_[r] * sc_ + rs;
            m_[r] = mn;
            al[r] = sc_;
        }
#pragma unroll
        for (int n = 0; n < 8; n++) {
            f32x4 t = o[n];
            t[0] *= al[0]; t[1] *= al[1]; t[2] *= al[2]; t[3] *= al[3];
            o[n] = t;
        }

        bf16x8 pa[2];
#pragma unroll
        for (int kc = 0; kc < 2; ++kc)
            pa[kc] = *(const bf16x8*)(Psw + l15 * 64 + (((kc * 4 + grp) ^ (l15 & 7)) * 8));
#pragma unroll
        for (int n = 0; n < 8; ++n) {
            int d = n * 16 + l15;
#pragma unroll
            for (int kc = 0; kc < 2; ++kc) {
                bf16x8 vb = *(const bf16x8*)(Vc + d * 64 + (((kc * 4 + grp) ^ (d & 7)) * 8));
                o[n] = MFMA16x32(pa[kc], vb, o[n]);
            }
        }

        if (lastT) {
            float inv[4];
#pragma unroll
            for (int r = 0; r < 4; ++r) inv[r] = 1.0f / l_[r];
            short* cb_ = ctx + (size_t)(b * S + qw + grp * 4) * D + h * HD + l15;
#pragma unroll
            for (int n = 0; n < 8; ++n)
#pragma unroll
                for (int r = 0; r < 4; ++r)
                    cb_[(size_t)r * D + n * 16] = f2bs(o[n][r] * inv[r]);
            if (i < 32) {
                qt = 31 - qtH;
                qw = qt * 64 + wid * 16;
                const short* qrow = qp + (size_t)(b * S + qw + l15) * LD + h * HD;
#pragma unroll
                for (int kc = 0; kc < 4; kc++) aq[kc] = *(const bf16x8*)(qrow + kc * 32 + grp * 8);
#pragma unroll
                for (int r = 0; r < 4; r++) { m_[r] = NEGINF; l_[r] = 0.f; }
#pragma unroll
                for (int n = 0; n < 8; n++) o[n] = zero;
            }
        }
        __syncthreads();
        cur ^= 1;
    }
}

// ---------------------------------------------------------------------------
extern "C" void kernel_launch(void* const* d_in, const int* in_sizes, int n_in,
                              void* d_out, int out_size, void* d_ws, size_t ws_size,
                              hipStream_t stream) {
    const float* x    = (const float*)d_in[0];
    const float* wq   = (const float*)d_in[1];
    const float* wk   = (const float*)d_in[2];
    const float* wv   = (const float*)d_in[3];
    const float* wo   = (const float*)d_in[4];
    const float* bo   = (const float*)d_in[5];
    const float* w1   = (const float*)d_in[6];
    const float* b1   = (const float*)d_in[7];
    const float* w2   = (const float*)d_in[8];
    const float* b2   = (const float*)d_in[9];
    const float* lnsc = (const float*)d_in[10];
    const float* lnsh = (const float*)d_in[11];

    const int B = 2, S = 2048, D = 2048;
    const int M = B * S;  // 4096
    const int LDS_BIG = 2 * (256 * 64 + 256 * 64) * 2;  // 131072
    const int LDS_SML = 2 * (128 * 64 + 256 * 64) * 2;  // 98304

    char* p = (char*)d_ws;
    short* wqkvT = (short*)p; p += (size_t)3 * D * D * 2;   // dead after qkv gemm
    short* woT   = (short*)p; p += (size_t)D * D * 2;
    short* w1T   = (short*)p; p += (size_t)4 * D * D * 2;
    short* w2T   = (short*)p; p += (size_t)4 * D * D * 2;
    short* lnb   = (short*)p; p += (size_t)M * D * 2;
    short* qkvb  = (short*)p;
    short* h1    = qkvb;                                    // reuse qkv+ctx span
    p += (size_t)M * 3 * D * 2;
    short* ctxb  = (short*)p; p += (size_t)M * D * 2;
    float* x2    = (float*)p; p += (size_t)M * D * 4;

    short* Kh = wqkvT;          // overlays wqkvT (dead after qkv gemm)
    short* Vt = (short*)x2;     // overlays x2 (written only by proj, after flash)

    const float gconst = tanhf(sqrtf(2.0f / 3.14159265358979323846f));

    hipFuncSetAttribute((const void*)&gemm8p<256, 256, 0>, hipFuncAttributeMaxDynamicSharedMemorySize, LDS_BIG);
    hipFuncSetAttribute((const void*)&gemm8p<256, 256, 2>, hipFuncAttributeMaxDynamicSharedMemorySize, LDS_BIG);
    hipFuncSetAttribute((const void*)&gemm8p<128, 256, 1>, hipFuncAttributeMaxDynamicSharedMemorySize, LDS_SML);

    dim3 blk(256);
    transpose_kernel<<<dim3(64, 64), blk, 0, stream>>>(wq, wqkvT, D, D);
    transpose_kernel<<<dim3(64, 64), blk, 0, stream>>>(wk, wqkvT + (size_t)D * D, D, D);
    transpose_kernel<<<dim3(64, 64), blk, 0, stream>>>(wv, wqkvT + (size_t)2 * D * D, D, D);
    transpose_kernel<<<dim3(64, 64), blk, 0, stream>>>(wo, woT, D, D);
    transpose_kernel<<<dim3(256, 64), blk, 0, stream>>>(w1, w1T, D, 4 * D);
    transpose_kernel<<<dim3(64, 256), blk, 0, stream>>>(w2, w2T, 4 * D, D);

    ln_kernel<<<dim3(M), blk, 0, stream>>>(x, lnsc, lnsh, lnb);
    // qkv: grid 24x16 (384)
    gemm8p<256, 256, 0><<<dim3(3 * D / 256, M / 256), dim3(512), LDS_BIG, stream>>>(
        lnb, wqkvT, M, 3 * D, D, qkvb, nullptr, nullptr, 0.f);

    reshape_k_kernel<<<dim3(4096), blk, 0, stream>>>(qkvb, Kh);
    reshape_v_kernel<<<dim3(8192), blk, 0, stream>>>(qkvb, Vt);

    flash3_kernel<<<dim3(512), blk, 0, stream>>>(qkvb, Kh, Vt, ctxb);

    // proj: grid 8x32 (256)
    gemm8p<128, 256, 1><<<dim3(D / 256, M / 128), dim3(512), LDS_SML, stream>>>(
        ctxb, woT, M, D, D, x2, bo, x, 0.f);
    ln_kernel<<<dim3(M), blk, 0, stream>>>(x2, lnsc, lnsh, lnb);
    // ffn1: grid 32x16 (512)
    gemm8p<256, 256, 2><<<dim3(4 * D / 256, M / 256), dim3(512), LDS_BIG, stream>>>(
        lnb, w1T, M, 4 * D, D, h1, b1, nullptr, gconst);
    // ffn2: grid 8x32 (256)
    gemm8p<128, 256, 1><<<dim3(D / 256, M / 128), dim3(512), LDS_SML, stream>>>(
        h1, w2T, M, D, 4 * D, (float*)d_out, b2, x2, 0.f);
}

// Round 8
// 666.448 us; speedup vs baseline: 1.0214x; 1.0214x over previous
//
#include <hip/hip_runtime.h>
#include <hip/hip_bf16.h>
#include <math.h>

// ---------------------------------------------------------------------------
// TransformerBlock fwd: ln1 -> qkv gemm -> causal flash attn -> proj+res
//   -> ln2 -> ffn1(buggy-gelu) -> ffn2+res.  bf16 MFMA, fp32 softmax/LN.
// R8: back to R4's proven 2-barrier/K-tile deep pipeline; raise MFMA per
//   barrier instead of phase count.  gemm256: 256x256, 8 waves, 64 MFMA/
//   wave/tile, 2-deep dbuf (128KB), vmcnt(8).  ffn2 = split-K x2 into a
//   partial buffer + combine pass (no atomics).  proj = R4 256x128 3-deep.
// ---------------------------------------------------------------------------

typedef short bf16x8 __attribute__((ext_vector_type(8)));
typedef float f32x4 __attribute__((ext_vector_type(4)));
typedef short short4v __attribute__((ext_vector_type(4)));

#define MFMA16x32(a, b, c) __builtin_amdgcn_mfma_f32_16x16x32_bf16((a), (b), (c), 0, 0, 0)

__device__ __forceinline__ short f2bs(float f) {
    unsigned u = __builtin_bit_cast(unsigned, f);
    unsigned r = (u + 0x7FFFu + ((u >> 16) & 1u)) >> 16;
    return (short)(unsigned short)r;
}

__device__ __forceinline__ void gload_lds16(const void* g, void* l) {
    __builtin_amdgcn_global_load_lds(
        (const __attribute__((address_space(1))) unsigned int*)g,
        (__attribute__((address_space(3))) unsigned int*)l, 16, 0, 0);
}

template <int N>
__device__ __forceinline__ void vmw() {
    if constexpr (N == 0) asm volatile("s_waitcnt vmcnt(0)" ::: "memory");
    else if constexpr (N == 6) asm volatile("s_waitcnt vmcnt(6)" ::: "memory");
    else if constexpr (N == 8) asm volatile("s_waitcnt vmcnt(8)" ::: "memory");
    else if constexpr (N == 12) asm volatile("s_waitcnt vmcnt(12)" ::: "memory");
}

// ---------- transpose fp32 (R x C) -> bf16 (C x R) ----------
__global__ __launch_bounds__(256) void transpose_kernel(const float* __restrict__ in,
                                                        short* __restrict__ out,
                                                        int R, int C) {
    __shared__ float tile[32][33];
    const int tx = threadIdx.x & 31;
    const int ty = threadIdx.x >> 5;
    const int c0 = blockIdx.x * 32;
    const int r0 = blockIdx.y * 32;
#pragma unroll
    for (int i = 0; i < 4; ++i) {
        int r = ty + i * 8;
        tile[r][tx] = in[(size_t)(r0 + r) * C + c0 + tx];
    }
    __syncthreads();
#pragma unroll
    for (int i = 0; i < 4; ++i) {
        int r = ty + i * 8;
        out[(size_t)(c0 + r) * R + r0 + tx] = f2bs(tile[tx][r]);
    }
}

// ---------- layernorm fp32 row (D=2048) -> bf16 row ----------
__global__ __launch_bounds__(256) void ln_kernel(const float* __restrict__ x,
                                                 const float* __restrict__ sc,
                                                 const float* __restrict__ sh,
                                                 short* __restrict__ out) {
    const int D = 2048;
    const int row = blockIdx.x;
    const int tid = threadIdx.x;
    __shared__ float red[4];
    const float4* xr = (const float4*)(x + (size_t)row * D);
    float4 v0 = xr[tid];
    float4 v1 = xr[tid + 256];
    float vals0[4] = {v0.x, v0.y, v0.z, v0.w};
    float vals1[4] = {v1.x, v1.y, v1.z, v1.w};

    float s = vals0[0] + vals0[1] + vals0[2] + vals0[3] + vals1[0] + vals1[1] + vals1[2] + vals1[3];
#pragma unroll
    for (int off = 32; off; off >>= 1) s += __shfl_xor(s, off);
    if ((tid & 63) == 0) red[tid >> 6] = s;
    __syncthreads();
    float mean = (red[0] + red[1] + red[2] + red[3]) * (1.0f / 2048.0f);
    __syncthreads();

    float q = 0.0f;
#pragma unroll
    for (int j = 0; j < 4; ++j) {
        float t0 = vals0[j] - mean;
        float t1 = vals1[j] - mean;
        q += t0 * t0 + t1 * t1;
    }
#pragma unroll
    for (int off = 32; off; off >>= 1) q += __shfl_xor(q, off);
    if ((tid & 63) == 0) red[tid >> 6] = q;
    __syncthreads();
    float var = (red[0] + red[1] + red[2] + red[3]) * (1.0f / 2048.0f);
    float inv = rsqrtf(var + 1e-5f);

    const int c0 = tid * 4;
    const int c1 = (tid + 256) * 4;
    short4v o0, o1;
#pragma unroll
    for (int j = 0; j < 4; ++j) {
        o0[j] = f2bs(sc[c0 + j] * ((vals0[j] - mean) * inv) + sh[c0 + j]);
        o1[j] = f2bs(sc[c1 + j] * ((vals1[j] - mean) * inv) + sh[c1 + j]);
    }
    *(short4v*)(out + (size_t)row * D + c0) = o0;
    *(short4v*)(out + (size_t)row * D + c1) = o1;
}

// ---------- gemm256: 256x256 tile, 2-deep dbuf, 64 MFMA/wave/K-tile --------
// C[M,N] = A[M,K] @ Bt[N,K]^T.  512 thr = 8 waves (2M x 4N), wave tile 128x64.
// EPI 0: bf16   EPI 2: bf16 gelu(acc+bias)
// SK==2: split-K; ksl=0 -> fp32 out = acc+bias+res; ksl=1 -> fp32 part = acc.
template <int EPI, int SK>
__global__ __launch_bounds__(512, 2) void gemm256(const short* __restrict__ Aop,
                                                  const short* __restrict__ Bt,
                                                  int M, int N, int K,
                                                  void* __restrict__ Cout,
                                                  float* __restrict__ part,
                                                  const float* __restrict__ bias,
                                                  const float* __restrict__ res,
                                                  float gconst) {
    constexpr int TSZ = 256 * 64;  // shorts per operand per buffer
    extern __shared__ __align__(16) short lds[];  // [A0|A1|B0|B1] = 128 KB
    const int tid = threadIdx.x;
    const int lane = tid & 63;
    const int wid = tid >> 6;
    const int wm = wid >> 2, wn = wid & 3;
    const int l15 = lane & 15, grp = lane >> 4;

    // T1 XCD-bijective remap (grid %8 == 0 for all launches here)
    const int gx = gridDim.x;
    int flat = (int)blockIdx.y * gx + (int)blockIdx.x;
    const int cpx = (gx * (int)gridDim.y) >> 3;
    flat = (flat & 7) * cpx + (flat >> 3);
    const int bx = flat % gx;
    const int byy = flat / gx;
    const int mtiles = M >> 8;
    const int myb = byy % mtiles;
    const int ksl = byy / mtiles;
    const long m0 = (long)myb * 256, n0 = (long)bx * 256;
    const int KS = K / SK;
    const long kbase = (long)ksl * KS;
    const int nt = KS >> 6;

    f32x4 zero = {0.f, 0.f, 0.f, 0.f};
    f32x4 acc[8][4];
#pragma unroll
    for (int i = 0; i < 8; i++)
#pragma unroll
        for (int j = 0; j < 4; j++) acc[i][j] = zero;

    auto STAGE = [&](int t, short* bufA, short* bufB) {
        const long k0 = kbase + ((long)t << 6);
#pragma unroll
        for (int j = 0; j < 4; ++j) {
            int c = tid + j * 512;
            int row = c >> 3, sl = (c & 7) ^ (row & 7);
            gload_lds16(Aop + (size_t)(m0 + row) * K + k0 + sl * 8, bufA + (size_t)c * 8);
        }
#pragma unroll
        for (int j = 0; j < 4; ++j) {
            int c = tid + j * 512;
            int row = c >> 3, sl = (c & 7) ^ (row & 7);
            gload_lds16(Bt + (size_t)(n0 + row) * K + k0 + sl * 8, bufB + (size_t)c * 8);
        }
    };

    STAGE(0, lds, lds + 2 * TSZ);
    STAGE(1, lds + TSZ, lds + 3 * TSZ);

    for (int t = 0; t < nt; ++t) {
        if (t == nt - 1) { vmw<0>(); } else { vmw<8>(); }
        __builtin_amdgcn_s_barrier();
        __builtin_amdgcn_sched_barrier(0);
        const short* bufA = lds + (t & 1) * TSZ;
        const short* bufB = lds + 2 * TSZ + (t & 1) * TSZ;
        __builtin_amdgcn_s_setprio(1);
#pragma unroll
        for (int kk = 0; kk < 2; ++kk) {
            bf16x8 af[8], bfr[4];
#pragma unroll
            for (int mi = 0; mi < 8; ++mi) {
                int row = wm * 128 + mi * 16 + l15;
                af[mi] = *(const bf16x8*)(bufA + row * 64 + (((kk * 4 + grp) ^ (row & 7)) * 8));
            }
#pragma unroll
            for (int ni = 0; ni < 4; ++ni) {
                int row = wn * 64 + ni * 16 + l15;
                bfr[ni] = *(const bf16x8*)(bufB + row * 64 + (((kk * 4 + grp) ^ (row & 7)) * 8));
            }
#pragma unroll
            for (int mi = 0; mi < 8; ++mi)
#pragma unroll
                for (int ni = 0; ni < 4; ++ni)
                    acc[mi][ni] = MFMA16x32(af[mi], bfr[ni], acc[mi][ni]);
        }
        __builtin_amdgcn_s_setprio(0);
        asm volatile("s_waitcnt lgkmcnt(0)" ::: "memory");
        __builtin_amdgcn_sched_barrier(0);
        __builtin_amdgcn_s_barrier();
        if (t + 2 < nt) STAGE(t + 2, lds + (t & 1) * TSZ, lds + 2 * TSZ + (t & 1) * TSZ);
    }

#pragma unroll
    for (int mi = 0; mi < 8; mi++) {
        long gr = m0 + wm * 128 + mi * 16 + grp * 4;
#pragma unroll
        for (int ni = 0; ni < 4; ni++) {
            long gcol = n0 + wn * 64 + ni * 16 + l15;
#pragma unroll
            for (int r = 0; r < 4; r++) {
                float vv = acc[mi][ni][r];
                long idx = (gr + r) * N + gcol;
                if constexpr (SK == 2) {
                    if (ksl == 1) part[idx] = vv;
                    else ((float*)Cout)[idx] = vv + bias[gcol] + res[idx];
                } else if constexpr (EPI == 0) {
                    ((short*)Cout)[idx] = f2bs(vv);
                } else {
                    float tv = vv + bias[gcol];
                    float g = 0.5f * tv * (1.0f + gconst * (tv + 0.044715f * tv * tv * tv));
                    ((short*)Cout)[idx] = f2bs(g);
                }
            }
        }
    }
}

// ---------- gemm3d: R4's 256x128 3-deep pipeline (proj) ----------
template <int EPI>
__global__ __launch_bounds__(512, 1) void gemm3d(const short* __restrict__ A,
                                                 const short* __restrict__ Bt,
                                                 int M, int N, int K,
                                                 void* __restrict__ Cout,
                                                 const float* __restrict__ bias,
                                                 const float* __restrict__ res,
                                                 float gconst) {
    extern __shared__ __align__(16) short lds[];  // 3 * 24576 shorts
    const int tid = threadIdx.x;
    const int lane = tid & 63;
    const int wid = tid >> 6;
    const int wm = wid >> 1, wn = wid & 1;
    const int l15 = lane & 15, grp = lane >> 4;

    const int gx = gridDim.x;
    int flat = (int)blockIdx.y * gx + (int)blockIdx.x;
    const int cpx = (gx * (int)gridDim.y) >> 3;
    flat = (flat & 7) * cpx + (flat >> 3);
    const int bx = flat % gx, by = flat / gx;
    const long m0 = (long)by * 256, n0 = (long)bx * 128;

    f32x4 zero = {0.f, 0.f, 0.f, 0.f};
    f32x4 acc[4][4];
#pragma unroll
    for (int i = 0; i < 4; i++)
#pragma unroll
        for (int j = 0; j < 4; j++) acc[i][j] = zero;

    auto STAGE = [&](long k0, int b) {
        short* bufA = lds + b * 24576;
        short* bufB = bufA + 16384;
#pragma unroll
        for (int j = 0; j < 4; ++j) {
            int c = tid + j * 512;
            int row = c >> 3, sl = (c & 7) ^ (row & 7);
            gload_lds16(A + (size_t)(m0 + row) * K + k0 + sl * 8,
                        bufA + (size_t)(wid * 64 + j * 512) * 8);
        }
#pragma unroll
        for (int j = 0; j < 2; ++j) {
            int c = tid + j * 512;
            int row = c >> 3, sl = (c & 7) ^ (row & 7);
            gload_lds16(Bt + (size_t)(n0 + row) * K + k0 + sl * 8,
                        bufB + (size_t)(wid * 64 + j * 512) * 8);
        }
    };

    const int nt = K >> 6;
    STAGE(0, 0);
    STAGE(64, 1);
    int cur = 0, nx2 = 2;

    for (int t = 0; t < nt; ++t) {
        if (t + 2 < nt) {
            STAGE((long)(t + 2) * 64, nx2);
            vmw<12>();
        } else if (t + 1 < nt) {
            vmw<6>();
        } else {
            vmw<0>();
        }
        __builtin_amdgcn_s_barrier();
        __builtin_amdgcn_sched_barrier(0);

        const short* bufA = lds + cur * 24576;
        const short* bufB = bufA + 16384;
        bf16x8 af[2][4], bfr[2][4];
#pragma unroll
        for (int kk = 0; kk < 2; ++kk) {
#pragma unroll
            for (int m = 0; m < 4; ++m) {
                int row = wm * 64 + m * 16 + l15;
                af[kk][m] = *(const bf16x8*)(bufA + row * 64 + (((kk * 4 + grp) ^ (row & 7)) * 8));
            }
#pragma unroll
            for (int n = 0; n < 4; ++n) {
                int row = wn * 64 + n * 16 + l15;
                bfr[kk][n] = *(const bf16x8*)(bufB + row * 64 + (((kk * 4 + grp) ^ (row & 7)) * 8));
            }
        }
        __builtin_amdgcn_s_setprio(1);
#pragma unroll
        for (int kk = 0; kk < 2; ++kk)
#pragma unroll
            for (int m = 0; m < 4; ++m)
#pragma unroll
                for (int n = 0; n < 4; ++n)
                    acc[m][n] = MFMA16x32(af[kk][m], bfr[kk][n], acc[m][n]);
        __builtin_amdgcn_s_setprio(0);
        asm volatile("s_waitcnt lgkmcnt(0)" ::: "memory");
        __builtin_amdgcn_s_barrier();
        __builtin_amdgcn_sched_barrier(0);
        cur = (cur == 2) ? 0 : cur + 1;
        nx2 = (nx2 == 2) ? 0 : nx2 + 1;
    }

#pragma unroll
    for (int m = 0; m < 4; m++) {
        long gr = m0 + wm * 64 + m * 16 + grp * 4;
#pragma unroll
        for (int n = 0; n < 4; n++) {
            long gcol = n0 + wn * 64 + n * 16 + l15;
#pragma unroll
            for (int r = 0; r < 4; r++) {
                float vv = acc[m][n][r];
                long idx = (gr + r) * N + gcol;
                if (EPI == 0) {
                    ((short*)Cout)[idx] = f2bs(vv);
                } else if (EPI == 1) {
                    ((float*)Cout)[idx] = vv + bias[gcol] + res[idx];
                } else {
                    float t2 = vv + bias[gcol];
                    float g = 0.5f * t2 * (1.0f + gconst * (t2 + 0.044715f * t2 * t2 * t2));
                    ((short*)Cout)[idx] = f2bs(g);
                }
            }
        }
    }
}

// ---------- combine: out[i] += part[i] (fp32, vectorized) ----------
__global__ __launch_bounds__(256) void add_kernel(float* __restrict__ out,
                                                  const float* __restrict__ part,
                                                  int n4) {
    int i = blockIdx.x * 256 + threadIdx.x;
    int stride = gridDim.x * 256;
    for (; i < n4; i += stride) {
        float4 a = ((const float4*)out)[i];
        float4 b = ((const float4*)part)[i];
        a.x += b.x; a.y += b.y; a.z += b.z; a.w += b.w;
        ((float4*)out)[i] = a;
    }
}

// ---------- reshape: qkv[4096,6144] K-cols -> Kh[32][2048][128] ----------
__global__ __launch_bounds__(256) void reshape_k_kernel(const short* __restrict__ qkv,
                                                        short* __restrict__ Kh) {
    size_t idx = ((size_t)blockIdx.x * 256 + threadIdx.x) * 8;
    int d = (int)(idx & 127);
    int s = (int)((idx >> 7) & 2047);
    int bh = (int)(idx >> 18);
    int b = bh >> 4, h = bh & 15;
    const short* src = qkv + (size_t)(b * 2048 + s) * 6144 + 2048 + h * 128 + d;
    *(bf16x8*)(Kh + idx) = *(const bf16x8*)src;
}

// ---------- reshape: qkv V-cols -> Vt[32][128][2048] (transposed) ----------
__global__ __launch_bounds__(256) void reshape_v_kernel(const short* __restrict__ qkv,
                                                        short* __restrict__ Vt) {
    __shared__ short tile[32][33];
    const int bid = blockIdx.x;
    const int dt = bid & 3, st = (bid >> 2) & 63, bh = bid >> 8;
    const int b = bh >> 4, h = bh & 15;
    const int s0 = st * 32, d0 = dt * 32;
    const int tx = threadIdx.x & 31, ty = threadIdx.x >> 5;
#pragma unroll
    for (int i = 0; i < 4; ++i) {
        int s = ty + i * 8;
        tile[s][tx] = qkv[(size_t)(b * 2048 + s0 + s) * 6144 + 4096 + h * 128 + d0 + tx];
    }
    __syncthreads();
#pragma unroll
    for (int i = 0; i < 4; ++i) {
        int d = ty + i * 8;
        Vt[((size_t)bh * 128 + d0 + d) * 2048 + s0 + tx] = tile[tx][d];
    }
}

// ---------- causal flash attention, paired q-tiles + double-buffered K/V ----
__global__ __launch_bounds__(256) void flash3_kernel(const short* __restrict__ qp,  // qkv, ld 6144
                                                     const short* __restrict__ Kh,  // [32][2048][128]
                                                     const short* __restrict__ Vt,  // [32][128][2048]
                                                     short* __restrict__ ctx) {
    const int S = 2048, D = 2048, HD = 128, LD = 6144;
    __shared__ __align__(16) short Ks[2][64 * 128];
    __shared__ __align__(16) short Vs[2][64 * 128];
    __shared__ __align__(16) short Ps[4][16 * 64];
    const int tid = threadIdx.x;
    const int lane = tid & 63, wid = tid >> 6;
    const int l15 = lane & 15, grp = lane >> 4;

    int bid = (int)blockIdx.x;
    bid = (bid & 7) * 64 + (bid >> 3);
    const int p = bid & 15, bh = bid >> 4;
    const int b = bh >> 4, h = bh & 15;
    const int qtH = 31 - p;
    const int nH = qtH + 1;
    const float scale = 0.08838834764831845f;
    const float NEGINF = -__builtin_inff();

    const short* Kbase = Kh + (size_t)bh * S * 128;
    const short* Vbase = Vt + (size_t)bh * 128 * S;
    short* Psw = &Ps[wid][0];

    f32x4 zero = {0.f, 0.f, 0.f, 0.f};
    bf16x8 aq[4];
    float m_[4], l_[4];
    f32x4 o[8];

    int qt = qtH;
    int qw = qt * 64 + wid * 16;
    {
        const short* qrow = qp + (size_t)(b * S + qw + l15) * LD + h * HD;
#pragma unroll
        for (int kc = 0; kc < 4; kc++) aq[kc] = *(const bf16x8*)(qrow + kc * 32 + grp * 8);
    }
#pragma unroll
    for (int r = 0; r < 4; r++) { m_[r] = NEGINF; l_[r] = 0.f; }
#pragma unroll
    for (int n = 0; n < 8; n++) o[n] = zero;

#pragma unroll
    for (int j = 0; j < 4; ++j) {
        int c = tid + j * 256;
        int r = c >> 4, sl = c & 15;
        gload_lds16(Kbase + (size_t)r * 128 + ((sl ^ (r & 7)) * 8),
                    Ks[0] + (size_t)(wid * 64 + j * 256) * 8);
    }
#pragma unroll
    for (int j = 0; j < 4; ++j) {
        int c = tid + j * 256;
        int d = c >> 3, sl = c & 7;
        gload_lds16(Vbase + (size_t)d * S + ((sl ^ (d & 7)) * 8),
                    Vs[0] + (size_t)(wid * 64 + j * 256) * 8);
    }
    __syncthreads();

    int cur = 0;
    for (int i = 0; i < 33; ++i) {
        const int kt = (i < nH) ? i : (i - nH);
        const bool lastT = (kt == qt);

        if (i + 1 < 33) {
            const int ktn = (i + 1 < nH) ? (i + 1) : (i + 1 - nH);
            const long kn0 = (long)ktn * 64;
            const short* Kg = Kbase + kn0 * 128;
            const short* Vg = Vbase + kn0;
            short* kd = Ks[cur ^ 1];
            short* vd = Vs[cur ^ 1];
#pragma unroll
            for (int j = 0; j < 4; ++j) {
                int c = tid + j * 256;
                int r = c >> 4, sl = c & 15;
                gload_lds16(Kg + (size_t)r * 128 + ((sl ^ (r & 7)) * 8),
                            kd + (size_t)(wid * 64 + j * 256) * 8);
            }
#pragma unroll
            for (int j = 0; j < 4; ++j) {
                int c = tid + j * 256;
                int d = c >> 3, sl = c & 7;
                gload_lds16(Vg + (size_t)d * S + ((sl ^ (d & 7)) * 8),
                            vd + (size_t)(wid * 64 + j * 256) * 8);
            }
        }

        const short* Kc = Ks[cur];
        const short* Vc = Vs[cur];

        f32x4 s[4] = {zero, zero, zero, zero};
#pragma unroll
        for (int n = 0; n < 4; ++n) {
            int r = n * 16 + l15;
#pragma unroll
            for (int kc = 0; kc < 4; ++kc) {
                bf16x8 kb = *(const bf16x8*)(Kc + r * 128 + (((kc * 4 + grp) ^ (r & 7)) * 8));
                s[n] = MFMA16x32(aq[kc], kb, s[n]);
            }
        }

        float al[4];
#pragma unroll
        for (int r = 0; r < 4; ++r) {
            float v[4];
#pragma unroll
            for (int n = 0; n < 4; ++n) v[n] = s[n][r] * scale;
            if (lastT) {
                int qrel = wid * 16 + grp * 4 + r;
#pragma unroll
                for (int n = 0; n < 4; ++n)
                    if (n * 16 + l15 > qrel) v[n] = NEGINF;
            }
            float mx = fmaxf(fmaxf(v[0], v[1]), fmaxf(v[2], v[3]));
            mx = fmaxf(mx, __shfl_xor(mx, 1));
            mx = fmaxf(mx, __shfl_xor(mx, 2));
            mx = fmaxf(mx, __shfl_xor(mx, 4));
            mx = fmaxf(mx, __shfl_xor(mx, 8));
            float mn = fmaxf(m_[r], mx);
            float sc_ = __expf(m_[r] - mn);
            float rs = 0.f;
            int q = grp * 4 + r;
#pragma unroll
            for (int n = 0; n < 4; ++n) {
                v[n] = __expf(v[n] - mn);
                rs += v[n];
                Psw[q * 64 + (((n * 2 + (l15 >> 3)) ^ (q & 7)) * 8) + (l15 & 7)] = f2bs(v[n]);
            }
            rs += __shfl_xor(rs, 1);
            rs += __shfl_xor(rs, 2);
            rs += __shfl_xor(rs, 4);
            rs += __shfl_xor(rs, 8);
            l_[r] = l_[r] * sc_ + rs;
            m_[r] = mn;
            al[r] = sc_;
        }
#pragma unroll
        for (int n = 0; n < 8; n++) {
            f32x4 t = o[n];
            t[0] *= al[0]; t[1] *= al[1]; t[2] *= al[2]; t[3] *= al[3];
            o[n] = t;
        }

        bf16x8 pa[2];
#pragma unroll
        for (int kc = 0; kc < 2; ++kc)
            pa[kc] = *(const bf16x8*)(Psw + l15 * 64 + (((kc * 4 + grp) ^ (l15 & 7)) * 8));
#pragma unroll
        for (int n = 0; n < 8; ++n) {
            int d = n * 16 + l15;
#pragma unroll
            for (int kc = 0; kc < 2; ++kc) {
                bf16x8 vb = *(const bf16x8*)(Vc + d * 64 + (((kc * 4 + grp) ^ (d & 7)) * 8));
                o[n] = MFMA16x32(pa[kc], vb, o[n]);
            }
        }

        if (lastT) {
            float inv[4];
#pragma unroll
            for (int r = 0; r < 4; ++r) inv[r] = 1.0f / l_[r];
            short* cb_ = ctx + (size_t)(b * S + qw + grp * 4) * D + h * HD + l15;
#pragma unroll
            for (int n = 0; n < 8; ++n)
#pragma unroll
                for (int r = 0; r < 4; ++r)
                    cb_[(size_t)r * D + n * 16] = f2bs(o[n][r] * inv[r]);
            if (i < 32) {
                qt = 31 - qtH;
                qw = qt * 64 + wid * 16;
                const short* qrow = qp + (size_t)(b * S + qw + l15) * LD + h * HD;
#pragma unroll
                for (int kc = 0; kc < 4; kc++) aq[kc] = *(const bf16x8*)(qrow + kc * 32 + grp * 8);
#pragma unroll
                for (int r = 0; r < 4; r++) { m_[r] = NEGINF; l_[r] = 0.f; }
#pragma unroll
                for (int n = 0; n < 8; n++) o[n] = zero;
            }
        }
        __syncthreads();
        cur ^= 1;
    }
}

// ---------------------------------------------------------------------------
extern "C" void kernel_launch(void* const* d_in, const int* in_sizes, int n_in,
                              void* d_out, int out_size, void* d_ws, size_t ws_size,
                              hipStream_t stream) {
    const float* x    = (const float*)d_in[0];
    const float* wq   = (const float*)d_in[1];
    const float* wk   = (const float*)d_in[2];
    const float* wv   = (const float*)d_in[3];
    const float* wo   = (const float*)d_in[4];
    const float* bo   = (const float*)d_in[5];
    const float* w1   = (const float*)d_in[6];
    const float* b1   = (const float*)d_in[7];
    const float* w2   = (const float*)d_in[8];
    const float* b2   = (const float*)d_in[9];
    const float* lnsc = (const float*)d_in[10];
    const float* lnsh = (const float*)d_in[11];

    const int B = 2, S = 2048, D = 2048;
    const int M = B * S;  // 4096
    const int LDS_256 = 4 * 256 * 64 * 2;   // 131072 (gemm256)
    const int LDS_3D  = 3 * 24576 * 2;      // 147456 (gemm3d)

    char* p = (char*)d_ws;
    short* wqkvT = (short*)p; p += (size_t)3 * D * D * 2;   // dead after qkv gemm
    short* woT   = (short*)p; p += (size_t)D * D * 2;       // dead after proj
    short* w1T   = (short*)p; p += (size_t)4 * D * D * 2;
    short* w2T   = (short*)p; p += (size_t)4 * D * D * 2;
    short* lnb   = (short*)p; p += (size_t)M * D * 2;
    short* qkvb  = (short*)p;
    short* h1    = qkvb;                                    // reuse qkv+ctx span
    p += (size_t)M * 3 * D * 2;
    short* ctxb  = (short*)p; p += (size_t)M * D * 2;
    float* x2    = (float*)p; p += (size_t)M * D * 4;

    short* Kh = wqkvT;          // overlays wqkvT (dead after qkv gemm)
    short* Vt = (short*)x2;     // overlays x2 (written only by proj, after flash)
    float* part = (float*)d_ws; // overlays wqkvT+woT (33.6MB, dead by ffn2)

    const float gconst = tanhf(sqrtf(2.0f / 3.14159265358979323846f));

    hipFuncSetAttribute((const void*)&gemm256<0, 1>, hipFuncAttributeMaxDynamicSharedMemorySize, LDS_256);
    hipFuncSetAttribute((const void*)&gemm256<2, 1>, hipFuncAttributeMaxDynamicSharedMemorySize, LDS_256);
    hipFuncSetAttribute((const void*)&gemm256<1, 2>, hipFuncAttributeMaxDynamicSharedMemorySize, LDS_256);
    hipFuncSetAttribute((const void*)&gemm3d<1>, hipFuncAttributeMaxDynamicSharedMemorySize, LDS_3D);

    dim3 blk(256);
    transpose_kernel<<<dim3(64, 64), blk, 0, stream>>>(wq, wqkvT, D, D);
    transpose_kernel<<<dim3(64, 64), blk, 0, stream>>>(wk, wqkvT + (size_t)D * D, D, D);
    transpose_kernel<<<dim3(64, 64), blk, 0, stream>>>(wv, wqkvT + (size_t)2 * D * D, D, D);
    transpose_kernel<<<dim3(64, 64), blk, 0, stream>>>(wo, woT, D, D);
    transpose_kernel<<<dim3(256, 64), blk, 0, stream>>>(w1, w1T, D, 4 * D);
    transpose_kernel<<<dim3(64, 256), blk, 0, stream>>>(w2, w2T, 4 * D, D);

    ln_kernel<<<dim3(M), blk, 0, stream>>>(x, lnsc, lnsh, lnb);
    // qkv: [4096,2048]@[2048,6144], 256x256 tiles -> grid 24x16 (384)
    gemm256<0, 1><<<dim3(3 * D / 256, M / 256), dim3(512), LDS_256, stream>>>(
        lnb, wqkvT, M, 3 * D, D, qkvb, nullptr, nullptr, nullptr, 0.f);

    reshape_k_kernel<<<dim3(4096), blk, 0, stream>>>(qkvb, Kh);
    reshape_v_kernel<<<dim3(8192), blk, 0, stream>>>(qkvb, Vt);

    flash3_kernel<<<dim3(512), blk, 0, stream>>>(qkvb, Kh, Vt, ctxb);

    // proj: 256x128 3-deep -> grid 16x16 (256)
    gemm3d<1><<<dim3(D / 128, M / 256), dim3(512), LDS_3D, stream>>>(
        ctxb, woT, M, D, D, x2, bo, x, 0.f);
    ln_kernel<<<dim3(M), blk, 0, stream>>>(x2, lnsc, lnsh, lnb);
    // ffn1: 256x256 -> grid 32x16 (512)
    gemm256<2, 1><<<dim3(4 * D / 256, M / 256), dim3(512), LDS_256, stream>>>(
        lnb, w1T, M, 4 * D, D, h1, nullptr, b1, nullptr, gconst);
    // ffn2: split-K x2, 256x256 -> grid 8x32 (256); ks0 -> d_out, ks1 -> part
    gemm256<1, 2><<<dim3(D / 256, 2 * M / 256), dim3(512), LDS_256, stream>>>(
        h1, w2T, M, D, 4 * D, (float*)d_out, part, b2, x2, 0.f);
    add_kernel<<<dim3(2048), blk, 0, stream>>>((float*)d_out, part, M * D / 4);
}

// Round 9
// 627.545 us; speedup vs baseline: 1.0847x; 1.0620x over previous
//
#include <hip/hip_runtime.h>
#include <hip/hip_bf16.h>
#include <math.h>

// ---------------------------------------------------------------------------
// TransformerBlock fwd: ln1 -> qkv gemm -> causal flash attn -> proj+res
//   -> ln2 -> ffn1(buggy-gelu) -> ffn2+res.  bf16 MFMA, fp32 softmax/LN.
// R9: work/idle elimination. qkv -> 256x128 (768 blocks = 3 full rounds);
//   ffn2 -> 256x128 single round (drops split-K part buffer + add pass);
//   reshape_k dropped (flash stages K straight from qkv, stride 6144).
// ---------------------------------------------------------------------------

typedef short bf16x8 __attribute__((ext_vector_type(8)));
typedef float f32x4 __attribute__((ext_vector_type(4)));
typedef short short4v __attribute__((ext_vector_type(4)));

#define MFMA16x32(a, b, c) __builtin_amdgcn_mfma_f32_16x16x32_bf16((a), (b), (c), 0, 0, 0)

__device__ __forceinline__ short f2bs(float f) {
    unsigned u = __builtin_bit_cast(unsigned, f);
    unsigned r = (u + 0x7FFFu + ((u >> 16) & 1u)) >> 16;
    return (short)(unsigned short)r;
}

__device__ __forceinline__ void gload_lds16(const void* g, void* l) {
    __builtin_amdgcn_global_load_lds(
        (const __attribute__((address_space(1))) unsigned int*)g,
        (__attribute__((address_space(3))) unsigned int*)l, 16, 0, 0);
}

template <int N>
__device__ __forceinline__ void vmw() {
    if constexpr (N == 0) asm volatile("s_waitcnt vmcnt(0)" ::: "memory");
    else if constexpr (N == 6) asm volatile("s_waitcnt vmcnt(6)" ::: "memory");
    else if constexpr (N == 8) asm volatile("s_waitcnt vmcnt(8)" ::: "memory");
    else if constexpr (N == 12) asm volatile("s_waitcnt vmcnt(12)" ::: "memory");
}

// ---------- transpose fp32 (R x C) -> bf16 (C x R) ----------
__global__ __launch_bounds__(256) void transpose_kernel(const float* __restrict__ in,
                                                        short* __restrict__ out,
                                                        int R, int C) {
    __shared__ float tile[32][33];
    const int tx = threadIdx.x & 31;
    const int ty = threadIdx.x >> 5;
    const int c0 = blockIdx.x * 32;
    const int r0 = blockIdx.y * 32;
#pragma unroll
    for (int i = 0; i < 4; ++i) {
        int r = ty + i * 8;
        tile[r][tx] = in[(size_t)(r0 + r) * C + c0 + tx];
    }
    __syncthreads();
#pragma unroll
    for (int i = 0; i < 4; ++i) {
        int r = ty + i * 8;
        out[(size_t)(c0 + r) * R + r0 + tx] = f2bs(tile[tx][r]);
    }
}

// ---------- layernorm fp32 row (D=2048) -> bf16 row ----------
__global__ __launch_bounds__(256) void ln_kernel(const float* __restrict__ x,
                                                 const float* __restrict__ sc,
                                                 const float* __restrict__ sh,
                                                 short* __restrict__ out) {
    const int D = 2048;
    const int row = blockIdx.x;
    const int tid = threadIdx.x;
    __shared__ float red[4];
    const float4* xr = (const float4*)(x + (size_t)row * D);
    float4 v0 = xr[tid];
    float4 v1 = xr[tid + 256];
    float vals0[4] = {v0.x, v0.y, v0.z, v0.w};
    float vals1[4] = {v1.x, v1.y, v1.z, v1.w};

    float s = vals0[0] + vals0[1] + vals0[2] + vals0[3] + vals1[0] + vals1[1] + vals1[2] + vals1[3];
#pragma unroll
    for (int off = 32; off; off >>= 1) s += __shfl_xor(s, off);
    if ((tid & 63) == 0) red[tid >> 6] = s;
    __syncthreads();
    float mean = (red[0] + red[1] + red[2] + red[3]) * (1.0f / 2048.0f);
    __syncthreads();

    float q = 0.0f;
#pragma unroll
    for (int j = 0; j < 4; ++j) {
        float t0 = vals0[j] - mean;
        float t1 = vals1[j] - mean;
        q += t0 * t0 + t1 * t1;
    }
#pragma unroll
    for (int off = 32; off; off >>= 1) q += __shfl_xor(q, off);
    if ((tid & 63) == 0) red[tid >> 6] = q;
    __syncthreads();
    float var = (red[0] + red[1] + red[2] + red[3]) * (1.0f / 2048.0f);
    float inv = rsqrtf(var + 1e-5f);

    const int c0 = tid * 4;
    const int c1 = (tid + 256) * 4;
    short4v o0, o1;
#pragma unroll
    for (int j = 0; j < 4; ++j) {
        o0[j] = f2bs(sc[c0 + j] * ((vals0[j] - mean) * inv) + sh[c0 + j]);
        o1[j] = f2bs(sc[c1 + j] * ((vals1[j] - mean) * inv) + sh[c1 + j]);
    }
    *(short4v*)(out + (size_t)row * D + c0) = o0;
    *(short4v*)(out + (size_t)row * D + c1) = o1;
}

// ---------- gemm256: 256x256 tile, 2-deep dbuf (ffn1) ----------
template <int EPI>
__global__ __launch_bounds__(512, 2) void gemm256(const short* __restrict__ Aop,
                                                  const short* __restrict__ Bt,
                                                  int M, int N, int K,
                                                  void* __restrict__ Cout,
                                                  const float* __restrict__ bias,
                                                  const float* __restrict__ res,
                                                  float gconst) {
    constexpr int TSZ = 256 * 64;
    extern __shared__ __align__(16) short lds[];  // [A0|A1|B0|B1] = 128 KB
    const int tid = threadIdx.x;
    const int lane = tid & 63;
    const int wid = tid >> 6;
    const int wm = wid >> 2, wn = wid & 3;
    const int l15 = lane & 15, grp = lane >> 4;

    const int gx = gridDim.x;
    int flat = (int)blockIdx.y * gx + (int)blockIdx.x;
    const int cpx = (gx * (int)gridDim.y) >> 3;
    flat = (flat & 7) * cpx + (flat >> 3);
    const int bx = flat % gx, by = flat / gx;
    const long m0 = (long)by * 256, n0 = (long)bx * 256;
    const int nt = K >> 6;

    f32x4 zero = {0.f, 0.f, 0.f, 0.f};
    f32x4 acc[8][4];
#pragma unroll
    for (int i = 0; i < 8; i++)
#pragma unroll
        for (int j = 0; j < 4; j++) acc[i][j] = zero;

    auto STAGE = [&](int t, short* bufA, short* bufB) {
        const long k0 = (long)t << 6;
#pragma unroll
        for (int j = 0; j < 4; ++j) {
            int c = tid + j * 512;
            int row = c >> 3, sl = (c & 7) ^ (row & 7);
            gload_lds16(Aop + (size_t)(m0 + row) * K + k0 + sl * 8, bufA + (size_t)c * 8);
        }
#pragma unroll
        for (int j = 0; j < 4; ++j) {
            int c = tid + j * 512;
            int row = c >> 3, sl = (c & 7) ^ (row & 7);
            gload_lds16(Bt + (size_t)(n0 + row) * K + k0 + sl * 8, bufB + (size_t)c * 8);
        }
    };

    STAGE(0, lds, lds + 2 * TSZ);
    STAGE(1, lds + TSZ, lds + 3 * TSZ);

    for (int t = 0; t < nt; ++t) {
        if (t == nt - 1) { vmw<0>(); } else { vmw<8>(); }
        __builtin_amdgcn_s_barrier();
        __builtin_amdgcn_sched_barrier(0);
        const short* bufA = lds + (t & 1) * TSZ;
        const short* bufB = lds + 2 * TSZ + (t & 1) * TSZ;
        __builtin_amdgcn_s_setprio(1);
#pragma unroll
        for (int kk = 0; kk < 2; ++kk) {
            bf16x8 af[8], bfr[4];
#pragma unroll
            for (int mi = 0; mi < 8; ++mi) {
                int row = wm * 128 + mi * 16 + l15;
                af[mi] = *(const bf16x8*)(bufA + row * 64 + (((kk * 4 + grp) ^ (row & 7)) * 8));
            }
#pragma unroll
            for (int ni = 0; ni < 4; ++ni) {
                int row = wn * 64 + ni * 16 + l15;
                bfr[ni] = *(const bf16x8*)(bufB + row * 64 + (((kk * 4 + grp) ^ (row & 7)) * 8));
            }
#pragma unroll
            for (int mi = 0; mi < 8; ++mi)
#pragma unroll
                for (int ni = 0; ni < 4; ++ni)
                    acc[mi][ni] = MFMA16x32(af[mi], bfr[ni], acc[mi][ni]);
        }
        __builtin_amdgcn_s_setprio(0);
        asm volatile("s_waitcnt lgkmcnt(0)" ::: "memory");
        __builtin_amdgcn_sched_barrier(0);
        __builtin_amdgcn_s_barrier();
        if (t + 2 < nt) STAGE(t + 2, lds + (t & 1) * TSZ, lds + 2 * TSZ + (t & 1) * TSZ);
    }

#pragma unroll
    for (int mi = 0; mi < 8; mi++) {
        long gr = m0 + wm * 128 + mi * 16 + grp * 4;
#pragma unroll
        for (int ni = 0; ni < 4; ni++) {
            long gcol = n0 + wn * 64 + ni * 16 + l15;
#pragma unroll
            for (int r = 0; r < 4; r++) {
                float vv = acc[mi][ni][r];
                long idx = (gr + r) * N + gcol;
                if constexpr (EPI == 0) {
                    ((short*)Cout)[idx] = f2bs(vv);
                } else if constexpr (EPI == 1) {
                    ((float*)Cout)[idx] = vv + bias[gcol] + res[idx];
                } else {
                    float tv = vv + bias[gcol];
                    float g = 0.5f * tv * (1.0f + gconst * (tv + 0.044715f * tv * tv * tv));
                    ((short*)Cout)[idx] = f2bs(g);
                }
            }
        }
    }
}

// ---------- gemm3d: 256x128, 3-deep pipeline (qkv / proj / ffn2) ----------
template <int EPI>
__global__ __launch_bounds__(512, 1) void gemm3d(const short* __restrict__ A,
                                                 const short* __restrict__ Bt,
                                                 int M, int N, int K,
                                                 void* __restrict__ Cout,
                                                 const float* __restrict__ bias,
                                                 const float* __restrict__ res,
                                                 float gconst) {
    extern __shared__ __align__(16) short lds[];  // 3 * 24576 shorts
    const int tid = threadIdx.x;
    const int lane = tid & 63;
    const int wid = tid >> 6;
    const int wm = wid >> 1, wn = wid & 1;
    const int l15 = lane & 15, grp = lane >> 4;

    const int gx = gridDim.x;
    int flat = (int)blockIdx.y * gx + (int)blockIdx.x;
    const int cpx = (gx * (int)gridDim.y) >> 3;
    flat = (flat & 7) * cpx + (flat >> 3);
    const int bx = flat % gx, by = flat / gx;
    const long m0 = (long)by * 256, n0 = (long)bx * 128;

    f32x4 zero = {0.f, 0.f, 0.f, 0.f};
    f32x4 acc[4][4];
#pragma unroll
    for (int i = 0; i < 4; i++)
#pragma unroll
        for (int j = 0; j < 4; j++) acc[i][j] = zero;

    auto STAGE = [&](long k0, int b) {
        short* bufA = lds + b * 24576;
        short* bufB = bufA + 16384;
#pragma unroll
        for (int j = 0; j < 4; ++j) {
            int c = tid + j * 512;
            int row = c >> 3, sl = (c & 7) ^ (row & 7);
            gload_lds16(A + (size_t)(m0 + row) * K + k0 + sl * 8,
                        bufA + (size_t)(wid * 64 + j * 512) * 8);
        }
#pragma unroll
        for (int j = 0; j < 2; ++j) {
            int c = tid + j * 512;
            int row = c >> 3, sl = (c & 7) ^ (row & 7);
            gload_lds16(Bt + (size_t)(n0 + row) * K + k0 + sl * 8,
                        bufB + (size_t)(wid * 64 + j * 512) * 8);
        }
    };

    const int nt = K >> 6;
    STAGE(0, 0);
    STAGE(64, 1);
    int cur = 0, nx2 = 2;

    for (int t = 0; t < nt; ++t) {
        if (t + 2 < nt) {
            STAGE((long)(t + 2) * 64, nx2);
            vmw<12>();
        } else if (t + 1 < nt) {
            vmw<6>();
        } else {
            vmw<0>();
        }
        __builtin_amdgcn_s_barrier();
        __builtin_amdgcn_sched_barrier(0);

        const short* bufA = lds + cur * 24576;
        const short* bufB = bufA + 16384;
        bf16x8 af[2][4], bfr[2][4];
#pragma unroll
        for (int kk = 0; kk < 2; ++kk) {
#pragma unroll
            for (int m = 0; m < 4; ++m) {
                int row = wm * 64 + m * 16 + l15;
                af[kk][m] = *(const bf16x8*)(bufA + row * 64 + (((kk * 4 + grp) ^ (row & 7)) * 8));
            }
#pragma unroll
            for (int n = 0; n < 4; ++n) {
                int row = wn * 64 + n * 16 + l15;
                bfr[kk][n] = *(const bf16x8*)(bufB + row * 64 + (((kk * 4 + grp) ^ (row & 7)) * 8));
            }
        }
        __builtin_amdgcn_s_setprio(1);
#pragma unroll
        for (int kk = 0; kk < 2; ++kk)
#pragma unroll
            for (int m = 0; m < 4; ++m)
#pragma unroll
                for (int n = 0; n < 4; ++n)
                    acc[m][n] = MFMA16x32(af[kk][m], bfr[kk][n], acc[m][n]);
        __builtin_amdgcn_s_setprio(0);
        asm volatile("s_waitcnt lgkmcnt(0)" ::: "memory");
        __builtin_amdgcn_s_barrier();
        __builtin_amdgcn_sched_barrier(0);
        cur = (cur == 2) ? 0 : cur + 1;
        nx2 = (nx2 == 2) ? 0 : nx2 + 1;
    }

#pragma unroll
    for (int m = 0; m < 4; m++) {
        long gr = m0 + wm * 64 + m * 16 + grp * 4;
#pragma unroll
        for (int n = 0; n < 4; n++) {
            long gcol = n0 + wn * 64 + n * 16 + l15;
#pragma unroll
            for (int r = 0; r < 4; r++) {
                float vv = acc[m][n][r];
                long idx = (gr + r) * N + gcol;
                if (EPI == 0) {
                    ((short*)Cout)[idx] = f2bs(vv);
                } else if (EPI == 1) {
                    ((float*)Cout)[idx] = vv + bias[gcol] + res[idx];
                } else {
                    float t2 = vv + bias[gcol];
                    float g = 0.5f * t2 * (1.0f + gconst * (t2 + 0.044715f * t2 * t2 * t2));
                    ((short*)Cout)[idx] = f2bs(g);
                }
            }
        }
    }
}

// ---------- reshape: qkv V-cols -> Vt[32][128][2048] (transposed) ----------
__global__ __launch_bounds__(256) void reshape_v_kernel(const short* __restrict__ qkv,
                                                        short* __restrict__ Vt) {
    __shared__ short tile[32][33];
    const int bid = blockIdx.x;
    const int dt = bid & 3, st = (bid >> 2) & 63, bh = bid >> 8;
    const int b = bh >> 4, h = bh & 15;
    const int s0 = st * 32, d0 = dt * 32;
    const int tx = threadIdx.x & 31, ty = threadIdx.x >> 5;
#pragma unroll
    for (int i = 0; i < 4; ++i) {
        int s = ty + i * 8;
        tile[s][tx] = qkv[(size_t)(b * 2048 + s0 + s) * 6144 + 4096 + h * 128 + d0 + tx];
    }
    __syncthreads();
#pragma unroll
    for (int i = 0; i < 4; ++i) {
        int d = ty + i * 8;
        Vt[((size_t)bh * 128 + d0 + d) * 2048 + s0 + tx] = tile[tx][d];
    }
}

// ---------- causal flash attention, paired q-tiles + double-buffered K/V ----
// K staged directly from qkv (row stride 6144); V from Vt[32][128][2048].
__global__ __launch_bounds__(256) void flash3_kernel(const short* __restrict__ qp,  // qkv, ld 6144
                                                     const short* __restrict__ Vt,
                                                     short* __restrict__ ctx) {
    const int S = 2048, D = 2048, HD = 128, LD = 6144;
    __shared__ __align__(16) short Ks[2][64 * 128];
    __shared__ __align__(16) short Vs[2][64 * 128];
    __shared__ __align__(16) short Ps[4][16 * 64];
    const int tid = threadIdx.x;
    const int lane = tid & 63, wid = tid >> 6;
    const int l15 = lane & 15, grp = lane >> 4;

    int bid = (int)blockIdx.x;
    bid = (bid & 7) * 64 + (bid >> 3);
    const int p = bid & 15, bh = bid >> 4;
    const int b = bh >> 4, h = bh & 15;
    const int qtH = 31 - p;
    const int nH = qtH + 1;
    const float scale = 0.08838834764831845f;
    const float NEGINF = -__builtin_inff();

    const short* Kbase = qp + (size_t)b * S * LD + 2048 + (size_t)h * HD;  // row s: + s*LD
    const short* Vbase = Vt + (size_t)bh * 128 * S;
    short* Psw = &Ps[wid][0];

    f32x4 zero = {0.f, 0.f, 0.f, 0.f};
    bf16x8 aq[4];
    float m_[4], l_[4];
    f32x4 o[8];

    int qt = qtH;
    int qw = qt * 64 + wid * 16;
    {
        const short* qrow = qp + (size_t)(b * S + qw + l15) * LD + h * HD;
#pragma unroll
        for (int kc = 0; kc < 4; kc++) aq[kc] = *(const bf16x8*)(qrow + kc * 32 + grp * 8);
    }
#pragma unroll
    for (int r = 0; r < 4; r++) { m_[r] = NEGINF; l_[r] = 0.f; }
#pragma unroll
    for (int n = 0; n < 8; n++) o[n] = zero;

#pragma unroll
    for (int j = 0; j < 4; ++j) {
        int c = tid + j * 256;
        int r = c >> 4, sl = c & 15;
        gload_lds16(Kbase + (size_t)r * LD + ((sl ^ (r & 7)) * 8),
                    Ks[0] + (size_t)(wid * 64 + j * 256) * 8);
    }
#pragma unroll
    for (int j = 0; j < 4; ++j) {
        int c = tid + j * 256;
        int d = c >> 3, sl = c & 7;
        gload_lds16(Vbase + (size_t)d * S + ((sl ^ (d & 7)) * 8),
                    Vs[0] + (size_t)(wid * 64 + j * 256) * 8);
    }
    __syncthreads();

    int cur = 0;
    for (int i = 0; i < 33; ++i) {
        const int kt = (i < nH) ? i : (i - nH);
        const bool lastT = (kt == qt);

        if (i + 1 < 33) {
            const int ktn = (i + 1 < nH) ? (i + 1) : (i + 1 - nH);
            const long kn0 = (long)ktn * 64;
            const short* Kg = Kbase + (size_t)kn0 * LD;
            const short* Vg = Vbase + kn0;
            short* kd = Ks[cur ^ 1];
            short* vd = Vs[cur ^ 1];
#pragma unroll
            for (int j = 0; j < 4; ++j) {
                int c = tid + j * 256;
                int r = c >> 4, sl = c & 15;
                gload_lds16(Kg + (size_t)r * LD + ((sl ^ (r & 7)) * 8),
                            kd + (size_t)(wid * 64 + j * 256) * 8);
            }
#pragma unroll
            for (int j = 0; j < 4; ++j) {
                int c = tid + j * 256;
                int d = c >> 3, sl = c & 7;
                gload_lds16(Vg + (size_t)d * S + ((sl ^ (d & 7)) * 8),
                            vd + (size_t)(wid * 64 + j * 256) * 8);
            }
        }

        const short* Kc = Ks[cur];
        const short* Vc = Vs[cur];

        f32x4 s[4] = {zero, zero, zero, zero};
#pragma unroll
        for (int n = 0; n < 4; ++n) {
            int r = n * 16 + l15;
#pragma unroll
            for (int kc = 0; kc < 4; ++kc) {
                bf16x8 kb = *(const bf16x8*)(Kc + r * 128 + (((kc * 4 + grp) ^ (r & 7)) * 8));
                s[n] = MFMA16x32(aq[kc], kb, s[n]);
            }
        }

        float al[4];
#pragma unroll
        for (int r = 0; r < 4; ++r) {
            float v[4];
#pragma unroll
            for (int n = 0; n < 4; ++n) v[n] = s[n][r] * scale;
            if (lastT) {
                int qrel = wid * 16 + grp * 4 + r;
#pragma unroll
                for (int n = 0; n < 4; ++n)
                    if (n * 16 + l15 > qrel) v[n] = NEGINF;
            }
            float mx = fmaxf(fmaxf(v[0], v[1]), fmaxf(v[2], v[3]));
            mx = fmaxf(mx, __shfl_xor(mx, 1));
            mx = fmaxf(mx, __shfl_xor(mx, 2));
            mx = fmaxf(mx, __shfl_xor(mx, 4));
            mx = fmaxf(mx, __shfl_xor(mx, 8));
            float mn = fmaxf(m_[r], mx);
            float sc_ = __expf(m_[r] - mn);
            float rs = 0.f;
            int q = grp * 4 + r;
#pragma unroll
            for (int n = 0; n < 4; ++n) {
                v[n] = __expf(v[n] - mn);
                rs += v[n];
                Psw[q * 64 + (((n * 2 + (l15 >> 3)) ^ (q & 7)) * 8) + (l15 & 7)] = f2bs(v[n]);
            }
            rs += __shfl_xor(rs, 1);
            rs += __shfl_xor(rs, 2);
            rs += __shfl_xor(rs, 4);
            rs += __shfl_xor(rs, 8);
            l_[r] = l_[r] * sc_ + rs;
            m_[r] = mn;
            al[r] = sc_;
        }
#pragma unroll
        for (int n = 0; n < 8; n++) {
            f32x4 t = o[n];
            t[0] *= al[0]; t[1] *= al[1]; t[2] *= al[2]; t[3] *= al[3];
            o[n] = t;
        }

        bf16x8 pa[2];
#pragma unroll
        for (int kc = 0; kc < 2; ++kc)
            pa[kc] = *(const bf16x8*)(Psw + l15 * 64 + (((kc * 4 + grp) ^ (l15 & 7)) * 8));
#pragma unroll
        for (int n = 0; n < 8; ++n) {
            int d = n * 16 + l15;
#pragma unroll
            for (int kc = 0; kc < 2; ++kc) {
                bf16x8 vb = *(const bf16x8*)(Vc + d * 64 + (((kc * 4 + grp) ^ (d & 7)) * 8));
                o[n] = MFMA16x32(pa[kc], vb, o[n]);
            }
        }

        if (lastT) {
            float inv[4];
#pragma unroll
            for (int r = 0; r < 4; ++r) inv[r] = 1.0f / l_[r];
            short* cb_ = ctx + (size_t)(b * S + qw + grp * 4) * D + h * HD + l15;
#pragma unroll
            for (int n = 0; n < 8; ++n)
#pragma unroll
                for (int r = 0; r < 4; ++r)
                    cb_[(size_t)r * D + n * 16] = f2bs(o[n][r] * inv[r]);
            if (i < 32) {
                qt = 31 - qtH;
                qw = qt * 64 + wid * 16;
                const short* qrow = qp + (size_t)(b * S + qw + l15) * LD + h * HD;
#pragma unroll
                for (int kc = 0; kc < 4; kc++) aq[kc] = *(const bf16x8*)(qrow + kc * 32 + grp * 8);
#pragma unroll
                for (int r = 0; r < 4; r++) { m_[r] = NEGINF; l_[r] = 0.f; }
#pragma unroll
                for (int n = 0; n < 8; n++) o[n] = zero;
            }
        }
        __syncthreads();
        cur ^= 1;
    }
}

// ---------------------------------------------------------------------------
extern "C" void kernel_launch(void* const* d_in, const int* in_sizes, int n_in,
                              void* d_out, int out_size, void* d_ws, size_t ws_size,
                              hipStream_t stream) {
    const float* x    = (const float*)d_in[0];
    const float* wq   = (const float*)d_in[1];
    const float* wk   = (const float*)d_in[2];
    const float* wv   = (const float*)d_in[3];
    const float* wo   = (const float*)d_in[4];
    const float* bo   = (const float*)d_in[5];
    const float* w1   = (const float*)d_in[6];
    const float* b1   = (const float*)d_in[7];
    const float* w2   = (const float*)d_in[8];
    const float* b2   = (const float*)d_in[9];
    const float* lnsc = (const float*)d_in[10];
    const float* lnsh = (const float*)d_in[11];

    const int B = 2, S = 2048, D = 2048;
    const int M = B * S;  // 4096
    const int LDS_256 = 4 * 256 * 64 * 2;   // 131072 (gemm256)
    const int LDS_3D  = 3 * 24576 * 2;      // 147456 (gemm3d)

    char* p = (char*)d_ws;
    short* wqkvT = (short*)p; p += (size_t)3 * D * D * 2;
    short* woT   = (short*)p; p += (size_t)D * D * 2;
    short* w1T   = (short*)p; p += (size_t)4 * D * D * 2;
    short* w2T   = (short*)p; p += (size_t)4 * D * D * 2;
    short* lnb   = (short*)p; p += (size_t)M * D * 2;
    short* qkvb  = (short*)p;
    short* h1    = qkvb;                                    // reuse qkv+ctx span
    p += (size_t)M * 3 * D * 2;
    short* ctxb  = (short*)p; p += (size_t)M * D * 2;
    float* x2    = (float*)p; p += (size_t)M * D * 4;

    short* Vt = (short*)x2;     // overlays x2 (written only by proj, after flash)

    const float gconst = tanhf(sqrtf(2.0f / 3.14159265358979323846f));

    hipFuncSetAttribute((const void*)&gemm256<2>, hipFuncAttributeMaxDynamicSharedMemorySize, LDS_256);
    hipFuncSetAttribute((const void*)&gemm3d<0>, hipFuncAttributeMaxDynamicSharedMemorySize, LDS_3D);
    hipFuncSetAttribute((const void*)&gemm3d<1>, hipFuncAttributeMaxDynamicSharedMemorySize, LDS_3D);

    dim3 blk(256);
    transpose_kernel<<<dim3(64, 64), blk, 0, stream>>>(wq, wqkvT, D, D);
    transpose_kernel<<<dim3(64, 64), blk, 0, stream>>>(wk, wqkvT + (size_t)D * D, D, D);
    transpose_kernel<<<dim3(64, 64), blk, 0, stream>>>(wv, wqkvT + (size_t)2 * D * D, D, D);
    transpose_kernel<<<dim3(64, 64), blk, 0, stream>>>(wo, woT, D, D);
    transpose_kernel<<<dim3(256, 64), blk, 0, stream>>>(w1, w1T, D, 4 * D);
    transpose_kernel<<<dim3(64, 256), blk, 0, stream>>>(w2, w2T, 4 * D, D);

    ln_kernel<<<dim3(M), blk, 0, stream>>>(x, lnsc, lnsh, lnb);
    // qkv: 256x128 -> grid 48x16 = 768 blocks (3 full rounds)
    gemm3d<0><<<dim3(3 * D / 128, M / 256), dim3(512), LDS_3D, stream>>>(
        lnb, wqkvT, M, 3 * D, D, qkvb, nullptr, nullptr, 0.f);

    reshape_v_kernel<<<dim3(8192), blk, 0, stream>>>(qkvb, Vt);

    flash3_kernel<<<dim3(512), blk, 0, stream>>>(qkvb, Vt, ctxb);

    // proj: 256x128 -> grid 16x16 (256)
    gemm3d<1><<<dim3(D / 128, M / 256), dim3(512), LDS_3D, stream>>>(
        ctxb, woT, M, D, D, x2, bo, x, 0.f);
    ln_kernel<<<dim3(M), blk, 0, stream>>>(x2, lnsc, lnsh, lnb);
    // ffn1: 256x256 -> grid 32x16 (512)
    gemm256<2><<<dim3(4 * D / 256, M / 256), dim3(512), LDS_256, stream>>>(
        lnb, w1T, M, 4 * D, D, h1, b1, nullptr, gconst);
    // ffn2: 256x128 single round -> grid 16x16 (256), 128 K-tiles
    gemm3d<1><<<dim3(D / 128, M / 256), dim3(512), LDS_3D, stream>>>(
        h1, w2T, M, D, 4 * D, (float*)d_out, b2, x2, 0.f);
}

// Round 10
// 625.708 us; speedup vs baseline: 1.0879x; 1.0029x over previous
//
#include <hip/hip_runtime.h>
#include <hip/hip_bf16.h>
#include <math.h>

// ---------------------------------------------------------------------------
// TransformerBlock fwd: ln1 -> qkv gemm -> causal flash attn -> proj+res
//   -> ln2 -> ffn1(buggy-gelu) -> ffn2+res.  bf16 MFMA, fp32 softmax/LN.
// R10: (1) ffn1 -> gemm3b: 256x128, BK=32, 3-deep, 72KB LDS => 2 blocks/CU
//      (cross-block overlap, m97 mechanism). (2) 6 transposes fused into one
//      launch. (3) x2 residual stream in bf16 (proj bf16-out epilogue,
//      bf16-in LN, ffn2 bf16-res epilogue).
// ---------------------------------------------------------------------------

typedef short bf16x8 __attribute__((ext_vector_type(8)));
typedef float f32x4 __attribute__((ext_vector_type(4)));
typedef short short4v __attribute__((ext_vector_type(4)));

#define MFMA16x32(a, b, c) __builtin_amdgcn_mfma_f32_16x16x32_bf16((a), (b), (c), 0, 0, 0)

__device__ __forceinline__ short f2bs(float f) {
    unsigned u = __builtin_bit_cast(unsigned, f);
    unsigned r = (u + 0x7FFFu + ((u >> 16) & 1u)) >> 16;
    return (short)(unsigned short)r;
}

__device__ __forceinline__ float bs2f(short s) {
    unsigned u = ((unsigned)(unsigned short)s) << 16;
    return __builtin_bit_cast(float, u);
}

__device__ __forceinline__ void gload_lds16(const void* g, void* l) {
    __builtin_amdgcn_global_load_lds(
        (const __attribute__((address_space(1))) unsigned int*)g,
        (__attribute__((address_space(3))) unsigned int*)l, 16, 0, 0);
}

template <int N>
__device__ __forceinline__ void vmw() {
    if constexpr (N == 0) asm volatile("s_waitcnt vmcnt(0)" ::: "memory");
    else if constexpr (N == 3) asm volatile("s_waitcnt vmcnt(3)" ::: "memory");
    else if constexpr (N == 6) asm volatile("s_waitcnt vmcnt(6)" ::: "memory");
    else if constexpr (N == 12) asm volatile("s_waitcnt vmcnt(12)" ::: "memory");
}

// ---------- fused: all six weight transposes fp32 (R x C) -> bf16 (C x R) ---
__global__ __launch_bounds__(256) void transpose_all_kernel(
    const float* __restrict__ wq, const float* __restrict__ wk,
    const float* __restrict__ wv, const float* __restrict__ wo,
    const float* __restrict__ w1, const float* __restrict__ w2,
    short* __restrict__ wqkvT, short* __restrict__ woT,
    short* __restrict__ w1T, short* __restrict__ w2T) {
    const int D = 2048;
    __shared__ float tile[32][33];
    int blk = blockIdx.x;
    const float* in;
    short* out;
    int R, C, bx, by;
    if (blk < 16384) {                     // wq/wk/wv/wo: 4 x 4096 blocks
        int r = blk >> 12;
        in = (r == 0) ? wq : (r == 1) ? wk : (r == 2) ? wv : wo;
        out = (r < 3) ? (wqkvT + (size_t)r * D * D) : woT;
        R = D; C = D;
        int lb = blk & 4095; bx = lb & 63; by = lb >> 6;
    } else if (blk < 32768) {              // w1 [2048][8192]: 16384 blocks
        in = w1; out = w1T; R = D; C = 4 * D;
        int lb = blk - 16384; bx = lb & 255; by = lb >> 8;
    } else {                               // w2 [8192][2048]: 16384 blocks
        in = w2; out = w2T; R = 4 * D; C = D;
        int lb = blk - 32768; bx = lb & 63; by = lb >> 6;
    }
    const int tx = threadIdx.x & 31;
    const int ty = threadIdx.x >> 5;
    const int c0 = bx * 32, r0 = by * 32;
#pragma unroll
    for (int i = 0; i < 4; ++i) {
        int r = ty + i * 8;
        tile[r][tx] = in[(size_t)(r0 + r) * C + c0 + tx];
    }
    __syncthreads();
#pragma unroll
    for (int i = 0; i < 4; ++i) {
        int r = ty + i * 8;
        out[(size_t)(c0 + r) * R + r0 + tx] = f2bs(tile[tx][r]);
    }
}

// ---------- layernorm fp32 row (D=2048) -> bf16 row ----------
__global__ __launch_bounds__(256) void ln_kernel(const float* __restrict__ x,
                                                 const float* __restrict__ sc,
                                                 const float* __restrict__ sh,
                                                 short* __restrict__ out) {
    const int D = 2048;
    const int row = blockIdx.x;
    const int tid = threadIdx.x;
    __shared__ float red[4];
    const float4* xr = (const float4*)(x + (size_t)row * D);
    float4 v0 = xr[tid];
    float4 v1 = xr[tid + 256];
    float vals0[4] = {v0.x, v0.y, v0.z, v0.w};
    float vals1[4] = {v1.x, v1.y, v1.z, v1.w};

    float s = vals0[0] + vals0[1] + vals0[2] + vals0[3] + vals1[0] + vals1[1] + vals1[2] + vals1[3];
#pragma unroll
    for (int off = 32; off; off >>= 1) s += __shfl_xor(s, off);
    if ((tid & 63) == 0) red[tid >> 6] = s;
    __syncthreads();
    float mean = (red[0] + red[1] + red[2] + red[3]) * (1.0f / 2048.0f);
    __syncthreads();

    float q = 0.0f;
#pragma unroll
    for (int j = 0; j < 4; ++j) {
        float t0 = vals0[j] - mean;
        float t1 = vals1[j] - mean;
        q += t0 * t0 + t1 * t1;
    }
#pragma unroll
    for (int off = 32; off; off >>= 1) q += __shfl_xor(q, off);
    if ((tid & 63) == 0) red[tid >> 6] = q;
    __syncthreads();
    float var = (red[0] + red[1] + red[2] + red[3]) * (1.0f / 2048.0f);
    float inv = rsqrtf(var + 1e-5f);

    const int c0 = tid * 4;
    const int c1 = (tid + 256) * 4;
    short4v o0, o1;
#pragma unroll
    for (int j = 0; j < 4; ++j) {
        o0[j] = f2bs(sc[c0 + j] * ((vals0[j] - mean) * inv) + sh[c0 + j]);
        o1[j] = f2bs(sc[c1 + j] * ((vals1[j] - mean) * inv) + sh[c1 + j]);
    }
    *(short4v*)(out + (size_t)row * D + c0) = o0;
    *(short4v*)(out + (size_t)row * D + c1) = o1;
}

// ---------- layernorm bf16 row (D=2048) -> bf16 row ----------
__global__ __launch_bounds__(256) void ln_bf16_kernel(const short* __restrict__ x,
                                                      const float* __restrict__ sc,
                                                      const float* __restrict__ sh,
                                                      short* __restrict__ out) {
    const int D = 2048;
    const int row = blockIdx.x;
    const int tid = threadIdx.x;
    __shared__ float red[4];
    bf16x8 v = *(const bf16x8*)(x + (size_t)row * D + tid * 8);
    float vals[8];
#pragma unroll
    for (int j = 0; j < 8; ++j) vals[j] = bs2f(v[j]);

    float s = 0.f;
#pragma unroll
    for (int j = 0; j < 8; ++j) s += vals[j];
#pragma unroll
    for (int off = 32; off; off >>= 1) s += __shfl_xor(s, off);
    if ((tid & 63) == 0) red[tid >> 6] = s;
    __syncthreads();
    float mean = (red[0] + red[1] + red[2] + red[3]) * (1.0f / 2048.0f);
    __syncthreads();

    float q = 0.0f;
#pragma unroll
    for (int j = 0; j < 8; ++j) {
        float t = vals[j] - mean;
        q += t * t;
    }
#pragma unroll
    for (int off = 32; off; off >>= 1) q += __shfl_xor(q, off);
    if ((tid & 63) == 0) red[tid >> 6] = q;
    __syncthreads();
    float var = (red[0] + red[1] + red[2] + red[3]) * (1.0f / 2048.0f);
    float inv = rsqrtf(var + 1e-5f);

    const int c0 = tid * 8;
    bf16x8 o;
#pragma unroll
    for (int j = 0; j < 8; ++j)
        o[j] = f2bs(sc[c0 + j] * ((vals[j] - mean) * inv) + sh[c0 + j]);
    *(bf16x8*)(out + (size_t)row * D + c0) = o;
}

// ---------- gemm3d: 256x128, BK=64, 3-deep pipeline (qkv / proj / ffn2) -----
// EPI 0: bf16  1: f32=acc+bias+f32res  2: bf16 gelu  3: bf16=acc+bias+f32res
// EPI 4: f32=acc+bias+bf16res (res reinterpreted as short*)
template <int EPI>
__global__ __launch_bounds__(512, 1) void gemm3d(const short* __restrict__ A,
                                                 const short* __restrict__ Bt,
                                                 int M, int N, int K,
                                                 void* __restrict__ Cout,
                                                 const float* __restrict__ bias,
                                                 const float* __restrict__ res,
                                                 float gconst) {
    extern __shared__ __align__(16) short lds[];  // 3 * 24576 shorts
    const int tid = threadIdx.x;
    const int lane = tid & 63;
    const int wid = tid >> 6;
    const int wm = wid >> 1, wn = wid & 1;
    const int l15 = lane & 15, grp = lane >> 4;

    const int gx = gridDim.x;
    int flat = (int)blockIdx.y * gx + (int)blockIdx.x;
    const int cpx = (gx * (int)gridDim.y) >> 3;
    flat = (flat & 7) * cpx + (flat >> 3);
    const int bx = flat % gx, by = flat / gx;
    const long m0 = (long)by * 256, n0 = (long)bx * 128;

    f32x4 zero = {0.f, 0.f, 0.f, 0.f};
    f32x4 acc[4][4];
#pragma unroll
    for (int i = 0; i < 4; i++)
#pragma unroll
        for (int j = 0; j < 4; j++) acc[i][j] = zero;

    auto STAGE = [&](long k0, int b) {
        short* bufA = lds + b * 24576;
        short* bufB = bufA + 16384;
#pragma unroll
        for (int j = 0; j < 4; ++j) {
            int c = tid + j * 512;
            int row = c >> 3, sl = (c & 7) ^ (row & 7);
            gload_lds16(A + (size_t)(m0 + row) * K + k0 + sl * 8,
                        bufA + (size_t)(wid * 64 + j * 512) * 8);
        }
#pragma unroll
        for (int j = 0; j < 2; ++j) {
            int c = tid + j * 512;
            int row = c >> 3, sl = (c & 7) ^ (row & 7);
            gload_lds16(Bt + (size_t)(n0 + row) * K + k0 + sl * 8,
                        bufB + (size_t)(wid * 64 + j * 512) * 8);
        }
    };

    const int nt = K >> 6;
    STAGE(0, 0);
    STAGE(64, 1);
    int cur = 0, nx2 = 2;

    for (int t = 0; t < nt; ++t) {
        if (t + 2 < nt) {
            STAGE((long)(t + 2) * 64, nx2);
            vmw<12>();
        } else if (t + 1 < nt) {
            vmw<6>();
        } else {
            vmw<0>();
        }
        __builtin_amdgcn_s_barrier();
        __builtin_amdgcn_sched_barrier(0);

        const short* bufA = lds + cur * 24576;
        const short* bufB = bufA + 16384;
        bf16x8 af[2][4], bfr[2][4];
#pragma unroll
        for (int kk = 0; kk < 2; ++kk) {
#pragma unroll
            for (int m = 0; m < 4; ++m) {
                int row = wm * 64 + m * 16 + l15;
                af[kk][m] = *(const bf16x8*)(bufA + row * 64 + (((kk * 4 + grp) ^ (row & 7)) * 8));
            }
#pragma unroll
            for (int n = 0; n < 4; ++n) {
                int row = wn * 64 + n * 16 + l15;
                bfr[kk][n] = *(const bf16x8*)(bufB + row * 64 + (((kk * 4 + grp) ^ (row & 7)) * 8));
            }
        }
        __builtin_amdgcn_s_setprio(1);
#pragma unroll
        for (int kk = 0; kk < 2; ++kk)
#pragma unroll
            for (int m = 0; m < 4; ++m)
#pragma unroll
                for (int n = 0; n < 4; ++n)
                    acc[m][n] = MFMA16x32(af[kk][m], bfr[kk][n], acc[m][n]);
        __builtin_amdgcn_s_setprio(0);
        asm volatile("s_waitcnt lgkmcnt(0)" ::: "memory");
        __builtin_amdgcn_s_barrier();
        __builtin_amdgcn_sched_barrier(0);
        cur = (cur == 2) ? 0 : cur + 1;
        nx2 = (nx2 == 2) ? 0 : nx2 + 1;
    }

#pragma unroll
    for (int m = 0; m < 4; m++) {
        long gr = m0 + wm * 64 + m * 16 + grp * 4;
#pragma unroll
        for (int n = 0; n < 4; n++) {
            long gcol = n0 + wn * 64 + n * 16 + l15;
#pragma unroll
            for (int r = 0; r < 4; r++) {
                float vv = acc[m][n][r];
                long idx = (gr + r) * N + gcol;
                if constexpr (EPI == 0) {
                    ((short*)Cout)[idx] = f2bs(vv);
                } else if constexpr (EPI == 1) {
                    ((float*)Cout)[idx] = vv + bias[gcol] + res[idx];
                } else if constexpr (EPI == 2) {
                    float t2 = vv + bias[gcol];
                    float g = 0.5f * t2 * (1.0f + gconst * (t2 + 0.044715f * t2 * t2 * t2));
                    ((short*)Cout)[idx] = f2bs(g);
                } else if constexpr (EPI == 3) {
                    ((short*)Cout)[idx] = f2bs(vv + bias[gcol] + res[idx]);
                } else {  // EPI == 4: bf16 residual
                    ((float*)Cout)[idx] = vv + bias[gcol] + bs2f(((const short*)res)[idx]);
                }
            }
        }
    }
}

// ---------- gemm3b: 256x128, BK=32, 3-deep, 72KB LDS -> 2 blocks/CU --------
// Swizzle: 4 slots/row; sl = (c&3) ^ ((row ^ (row>>2)) & 3)  (2-way residual)
template <int EPI>
__global__ __launch_bounds__(512, 4) void gemm3b(const short* __restrict__ A,
                                                 const short* __restrict__ Bt,
                                                 int M, int N, int K,
                                                 void* __restrict__ Cout,
                                                 const float* __restrict__ bias,
                                                 const float* __restrict__ res,
                                                 float gconst) {
    extern __shared__ __align__(16) short lds[];  // 3 * 12288 shorts = 72KB
    const int tid = threadIdx.x;
    const int lane = tid & 63;
    const int wid = tid >> 6;
    const int wm = wid >> 1, wn = wid & 1;
    const int l15 = lane & 15, grp = lane >> 4;

    const int gx = gridDim.x;
    int flat = (int)blockIdx.y * gx + (int)blockIdx.x;
    const int cpx = (gx * (int)gridDim.y) >> 3;
    flat = (flat & 7) * cpx + (flat >> 3);
    const int bx = flat % gx, by = flat / gx;
    const long m0 = (long)by * 256, n0 = (long)bx * 128;

    f32x4 zero = {0.f, 0.f, 0.f, 0.f};
    f32x4 acc[4][4];
#pragma unroll
    for (int i = 0; i < 4; i++)
#pragma unroll
        for (int j = 0; j < 4; j++) acc[i][j] = zero;

    auto STAGE = [&](int t, int b) {
        short* bufA = lds + b * 12288;
        short* bufB = bufA + 8192;
        const long k0 = (long)t << 5;
#pragma unroll
        for (int j = 0; j < 2; ++j) {
            int c = tid + j * 512;
            int row = c >> 2, sl = (c & 3) ^ ((row ^ (row >> 2)) & 3);
            gload_lds16(A + (size_t)(m0 + row) * K + k0 + sl * 8, bufA + (size_t)c * 8);
        }
        {
            int c = tid;
            int row = c >> 2, sl = (c & 3) ^ ((row ^ (row >> 2)) & 3);
            gload_lds16(Bt + (size_t)(n0 + row) * K + k0 + sl * 8, bufB + (size_t)c * 8);
        }
    };

    const int nt = K >> 5;
    STAGE(0, 0);
    STAGE(1, 1);
    int cur = 0, nx2 = 2;

    for (int t = 0; t < nt; ++t) {
        if (t + 2 < nt) {
            STAGE(t + 2, nx2);
            vmw<6>();
        } else if (t + 1 < nt) {
            vmw<3>();
        } else {
            vmw<0>();
        }
        __builtin_amdgcn_s_barrier();
        __builtin_amdgcn_sched_barrier(0);

        const short* bufA = lds + cur * 12288;
        const short* bufB = bufA + 8192;
        bf16x8 af[4], bfr[4];
#pragma unroll
        for (int m = 0; m < 4; ++m) {
            int row = wm * 64 + m * 16 + l15;
            af[m] = *(const bf16x8*)(bufA + row * 32 + (((grp ^ (row ^ (row >> 2))) & 3) * 8));
        }
#pragma unroll
        for (int n = 0; n < 4; ++n) {
            int row = wn * 64 + n * 16 + l15;
            bfr[n] = *(const bf16x8*)(bufB + row * 32 + (((grp ^ (row ^ (row >> 2))) & 3) * 8));
        }
        __builtin_amdgcn_s_setprio(1);
#pragma unroll
        for (int m = 0; m < 4; ++m)
#pragma unroll
            for (int n = 0; n < 4; ++n)
                acc[m][n] = MFMA16x32(af[m], bfr[n], acc[m][n]);
        __builtin_amdgcn_s_setprio(0);
        asm volatile("s_waitcnt lgkmcnt(0)" ::: "memory");
        __builtin_amdgcn_s_barrier();
        __builtin_amdgcn_sched_barrier(0);
        cur = (cur == 2) ? 0 : cur + 1;
        nx2 = (nx2 == 2) ? 0 : nx2 + 1;
    }

#pragma unroll
    for (int m = 0; m < 4; m++) {
        long gr = m0 + wm * 64 + m * 16 + grp * 4;
#pragma unroll
        for (int n = 0; n < 4; n++) {
            long gcol = n0 + wn * 64 + n * 16 + l15;
#pragma unroll
            for (int r = 0; r < 4; r++) {
                float vv = acc[m][n][r];
                long idx = (gr + r) * N + gcol;
                if constexpr (EPI == 0) {
                    ((short*)Cout)[idx] = f2bs(vv);
                } else if constexpr (EPI == 2) {
                    float t2 = vv + bias[gcol];
                    float g = 0.5f * t2 * (1.0f + gconst * (t2 + 0.044715f * t2 * t2 * t2));
                    ((short*)Cout)[idx] = f2bs(g);
                } else {
                    ((float*)Cout)[idx] = vv + bias[gcol] + res[idx];
                }
            }
        }
    }
}

// ---------- reshape: qkv V-cols -> Vt[32][128][2048] (transposed) ----------
__global__ __launch_bounds__(256) void reshape_v_kernel(const short* __restrict__ qkv,
                                                        short* __restrict__ Vt) {
    __shared__ short tile[32][33];
    const int bid = blockIdx.x;
    const int dt = bid & 3, st = (bid >> 2) & 63, bh = bid >> 8;
    const int b = bh >> 4, h = bh & 15;
    const int s0 = st * 32, d0 = dt * 32;
    const int tx = threadIdx.x & 31, ty = threadIdx.x >> 5;
#pragma unroll
    for (int i = 0; i < 4; ++i) {
        int s = ty + i * 8;
        tile[s][tx] = qkv[(size_t)(b * 2048 + s0 + s) * 6144 + 4096 + h * 128 + d0 + tx];
    }
    __syncthreads();
#pragma unroll
    for (int i = 0; i < 4; ++i) {
        int d = ty + i * 8;
        Vt[((size_t)bh * 128 + d0 + d) * 2048 + s0 + tx] = tile[tx][d];
    }
}

// ---------- causal flash attention, paired q-tiles + double-buffered K/V ----
__global__ __launch_bounds__(256) void flash3_kernel(const short* __restrict__ qp,  // qkv, ld 6144
                                                     const short* __restrict__ Vt,
                                                     short* __restrict__ ctx) {
    const int S = 2048, D = 2048, HD = 128, LD = 6144;
    __shared__ __align__(16) short Ks[2][64 * 128];
    __shared__ __align__(16) short Vs[2][64 * 128];
    __shared__ __align__(16) short Ps[4][16 * 64];
    const int tid = threadIdx.x;
    const int lane = tid & 63, wid = tid >> 6;
    const int l15 = lane & 15, grp = lane >> 4;

    int bid = (int)blockIdx.x;
    bid = (bid & 7) * 64 + (bid >> 3);
    const int p = bid & 15, bh = bid >> 4;
    const int b = bh >> 4, h = bh & 15;
    const int qtH = 31 - p;
    const int nH = qtH + 1;
    const float scale = 0.08838834764831845f;
    const float NEGINF = -__builtin_inff();

    const short* Kbase = qp + (size_t)b * S * LD + 2048 + (size_t)h * HD;
    const short* Vbase = Vt + (size_t)bh * 128 * S;
    short* Psw = &Ps[wid][0];

    f32x4 zero = {0.f, 0.f, 0.f, 0.f};
    bf16x8 aq[4];
    float m_[4], l_[4];
    f32x4 o[8];

    int qt = qtH;
    int qw = qt * 64 + wid * 16;
    {
        const short* qrow = qp + (size_t)(b * S + qw + l15) * LD + h * HD;
#pragma unroll
        for (int kc = 0; kc < 4; kc++) aq[kc] = *(const bf16x8*)(qrow + kc * 32 + grp * 8);
    }
#pragma unroll
    for (int r = 0; r < 4; r++) { m_[r] = NEGINF; l_[r] = 0.f; }
#pragma unroll
    for (int n = 0; n < 8; n++) o[n] = zero;

#pragma unroll
    for (int j = 0; j < 4; ++j) {
        int c = tid + j * 256;
        int r = c >> 4, sl = c & 15;
        gload_lds16(Kbase + (size_t)r * LD + ((sl ^ (r & 7)) * 8),
                    Ks[0] + (size_t)(wid * 64 + j * 256) * 8);
    }
#pragma unroll
    for (int j = 0; j < 4; ++j) {
        int c = tid + j * 256;
        int d = c >> 3, sl = c & 7;
        gload_lds16(Vbase + (size_t)d * S + ((sl ^ (d & 7)) * 8),
                    Vs[0] + (size_t)(wid * 64 + j * 256) * 8);
    }
    __syncthreads();

    int cur = 0;
    for (int i = 0; i < 33; ++i) {
        const int kt = (i < nH) ? i : (i - nH);
        const bool lastT = (kt == qt);

        if (i + 1 < 33) {
            const int ktn = (i + 1 < nH) ? (i + 1) : (i + 1 - nH);
            const long kn0 = (long)ktn * 64;
            const short* Kg = Kbase + (size_t)kn0 * LD;
            const short* Vg = Vbase + kn0;
            short* kd = Ks[cur ^ 1];
            short* vd = Vs[cur ^ 1];
#pragma unroll
            for (int j = 0; j < 4; ++j) {
                int c = tid + j * 256;
                int r = c >> 4, sl = c & 15;
                gload_lds16(Kg + (size_t)r * LD + ((sl ^ (r & 7)) * 8),
                            kd + (size_t)(wid * 64 + j * 256) * 8);
            }
#pragma unroll
            for (int j = 0; j < 4; ++j) {
                int c = tid + j * 256;
                int d = c >> 3, sl = c & 7;
                gload_lds16(Vg + (size_t)d * S + ((sl ^ (d & 7)) * 8),
                            vd + (size_t)(wid * 64 + j * 256) * 8);
            }
        }

        const short* Kc = Ks[cur];
        const short* Vc = Vs[cur];

        f32x4 s[4] = {zero, zero, zero, zero};
#pragma unroll
        for (int n = 0; n < 4; ++n) {
            int r = n * 16 + l15;
#pragma unroll
            for (int kc = 0; kc < 4; ++kc) {
                bf16x8 kb = *(const bf16x8*)(Kc + r * 128 + (((kc * 4 + grp) ^ (r & 7)) * 8));
                s[n] = MFMA16x32(aq[kc], kb, s[n]);
            }
        }

        float al[4];
#pragma unroll
        for (int r = 0; r < 4; ++r) {
            float v[4];
#pragma unroll
            for (int n = 0; n < 4; ++n) v[n] = s[n][r] * scale;
            if (lastT) {
                int qrel = wid * 16 + grp * 4 + r;
#pragma unroll
                for (int n = 0; n < 4; ++n)
                    if (n * 16 + l15 > qrel) v[n] = NEGINF;
            }
            float mx = fmaxf(fmaxf(v[0], v[1]), fmaxf(v[2], v[3]));
            mx = fmaxf(mx, __shfl_xor(mx, 1));
            mx = fmaxf(mx, __shfl_xor(mx, 2));
            mx = fmaxf(mx, __shfl_xor(mx, 4));
            mx = fmaxf(mx, __shfl_xor(mx, 8));
            float mn = fmaxf(m_[r], mx);
            float sc_ = __expf(m_[r] - mn);
            float rs = 0.f;
            int q = grp * 4 + r;
#pragma unroll
            for (int n = 0; n < 4; ++n) {
                v[n] = __expf(v[n] - mn);
                rs += v[n];
                Psw[q * 64 + (((n * 2 + (l15 >> 3)) ^ (q & 7)) * 8) + (l15 & 7)] = f2bs(v[n]);
            }
            rs += __shfl_xor(rs, 1);
            rs += __shfl_xor(rs, 2);
            rs += __shfl_xor(rs, 4);
            rs += __shfl_xor(rs, 8);
            l_[r] = l_[r] * sc_ + rs;
            m_[r] = mn;
            al[r] = sc_;
        }
#pragma unroll
        for (int n = 0; n < 8; n++) {
            f32x4 t = o[n];
            t[0] *= al[0]; t[1] *= al[1]; t[2] *= al[2]; t[3] *= al[3];
            o[n] = t;
        }

        bf16x8 pa[2];
#pragma unroll
        for (int kc = 0; kc < 2; ++kc)
            pa[kc] = *(const bf16x8*)(Psw + l15 * 64 + (((kc * 4 + grp) ^ (l15 & 7)) * 8));
#pragma unroll
        for (int n = 0; n < 8; ++n) {
            int d = n * 16 + l15;
#pragma unroll
            for (int kc = 0; kc < 2; ++kc) {
                bf16x8 vb = *(const bf16x8*)(Vc + d * 64 + (((kc * 4 + grp) ^ (d & 7)) * 8));
                o[n] = MFMA16x32(pa[kc], vb, o[n]);
            }
        }

        if (lastT) {
            float inv[4];
#pragma unroll
            for (int r = 0; r < 4; ++r) inv[r] = 1.0f / l_[r];
            short* cb_ = ctx + (size_t)(b * S + qw + grp * 4) * D + h * HD + l15;
#pragma unroll
            for (int n = 0; n < 8; ++n)
#pragma unroll
                for (int r = 0; r < 4; ++r)
                    cb_[(size_t)r * D + n * 16] = f2bs(o[n][r] * inv[r]);
            if (i < 32) {
                qt = 31 - qtH;
                qw = qt * 64 + wid * 16;
                const short* qrow = qp + (size_t)(b * S + qw + l15) * LD + h * HD;
#pragma unroll
                for (int kc = 0; kc < 4; kc++) aq[kc] = *(const bf16x8*)(qrow + kc * 32 + grp * 8);
#pragma unroll
                for (int r = 0; r < 4; r++) { m_[r] = NEGINF; l_[r] = 0.f; }
#pragma unroll
                for (int n = 0; n < 8; n++) o[n] = zero;
            }
        }
        __syncthreads();
        cur ^= 1;
    }
}

// ---------------------------------------------------------------------------
extern "C" void kernel_launch(void* const* d_in, const int* in_sizes, int n_in,
                              void* d_out, int out_size, void* d_ws, size_t ws_size,
                              hipStream_t stream) {
    const float* x    = (const float*)d_in[0];
    const float* wq   = (const float*)d_in[1];
    const float* wk   = (const float*)d_in[2];
    const float* wv   = (const float*)d_in[3];
    const float* wo   = (const float*)d_in[4];
    const float* bo   = (const float*)d_in[5];
    const float* w1   = (const float*)d_in[6];
    const float* b1   = (const float*)d_in[7];
    const float* w2   = (const float*)d_in[8];
    const float* b2   = (const float*)d_in[9];
    const float* lnsc = (const float*)d_in[10];
    const float* lnsh = (const float*)d_in[11];

    const int B = 2, S = 2048, D = 2048;
    const int M = B * S;  // 4096
    const int LDS_3D = 3 * 24576 * 2;   // 147456 (gemm3d)
    const int LDS_3B = 3 * 12288 * 2;   // 73728  (gemm3b)

    char* p = (char*)d_ws;
    short* wqkvT = (short*)p; p += (size_t)3 * D * D * 2;
    short* woT   = (short*)p; p += (size_t)D * D * 2;
    short* w1T   = (short*)p; p += (size_t)4 * D * D * 2;
    short* w2T   = (short*)p; p += (size_t)4 * D * D * 2;
    short* lnb   = (short*)p; p += (size_t)M * D * 2;
    short* qkvb  = (short*)p;
    short* h1    = qkvb;                                    // reuse qkv+ctx span
    p += (size_t)M * 3 * D * 2;
    short* ctxb  = (short*)p; p += (size_t)M * D * 2;
    short* x2    = (short*)p; p += (size_t)M * D * 2;       // bf16 residual stream

    short* Vt = x2;             // overlays x2 (16MB each; proj writes after flash)

    const float gconst = tanhf(sqrtf(2.0f / 3.14159265358979323846f));

    hipFuncSetAttribute((const void*)&gemm3d<0>, hipFuncAttributeMaxDynamicSharedMemorySize, LDS_3D);
    hipFuncSetAttribute((const void*)&gemm3d<3>, hipFuncAttributeMaxDynamicSharedMemorySize, LDS_3D);
    hipFuncSetAttribute((const void*)&gemm3d<4>, hipFuncAttributeMaxDynamicSharedMemorySize, LDS_3D);
    hipFuncSetAttribute((const void*)&gemm3b<2>, hipFuncAttributeMaxDynamicSharedMemorySize, LDS_3B);

    dim3 blk(256);
    transpose_all_kernel<<<dim3(49152), blk, 0, stream>>>(
        wq, wk, wv, wo, w1, w2, wqkvT, woT, w1T, w2T);

    ln_kernel<<<dim3(M), blk, 0, stream>>>(x, lnsc, lnsh, lnb);
    // qkv: 256x128 -> grid 48x16 = 768 blocks
    gemm3d<0><<<dim3(3 * D / 128, M / 256), dim3(512), LDS_3D, stream>>>(
        lnb, wqkvT, M, 3 * D, D, qkvb, nullptr, nullptr, 0.f);

    reshape_v_kernel<<<dim3(8192), blk, 0, stream>>>(qkvb, Vt);

    flash3_kernel<<<dim3(512), blk, 0, stream>>>(qkvb, Vt, ctxb);

    // proj: 256x128 -> grid 16x16 (256); bf16 out = acc + bo + x(fp32)
    gemm3d<3><<<dim3(D / 128, M / 256), dim3(512), LDS_3D, stream>>>(
        ctxb, woT, M, D, D, x2, bo, x, 0.f);
    ln_bf16_kernel<<<dim3(M), blk, 0, stream>>>(x2, lnsc, lnsh, lnb);
    // ffn1: gemm3b 256x128 BK=32, 2 blocks/CU -> grid 64x16 = 1024 (2 rounds)
    gemm3b<2><<<dim3(4 * D / 128, M / 256), dim3(512), LDS_3B, stream>>>(
        lnb, w1T, M, 4 * D, D, h1, b1, nullptr, gconst);
    // ffn2: 256x128 -> grid 16x16 (256); fp32 out = acc + b2 + x2(bf16)
    gemm3d<4><<<dim3(D / 128, M / 256), dim3(512), LDS_3D, stream>>>(
        h1, w2T, M, D, 4 * D, (float*)d_out, b2, (const float*)x2, 0.f);
}

// Round 11
// 598.537 us; speedup vs baseline: 1.1373x; 1.0454x over previous
//
#include <hip/hip_runtime.h>
#include <hip/hip_bf16.h>
#include <math.h>

// ---------------------------------------------------------------------------
// TransformerBlock fwd: ln1 -> qkv gemm -> causal flash attn -> proj+res
//   -> ln2 -> ffn1(buggy-gelu) -> ffn2+res.  bf16 MFMA, fp32 softmax/LN.
// R11: gemm2c for proj+ffn2: 128x128 tile, BK=64, 256 thr (4 waves, 64x64
//   wave tile), 2-deep dbuf @ 64KB LDS => 2 blocks/CU co-resident; one
//   block's MFMA covers the other's vmcnt/barrier drain. qkv=gemm3d,
//   ffn1=gemm3b unchanged (R10 anchor).
// ---------------------------------------------------------------------------

typedef short bf16x8 __attribute__((ext_vector_type(8)));
typedef float f32x4 __attribute__((ext_vector_type(4)));
typedef short short4v __attribute__((ext_vector_type(4)));

#define MFMA16x32(a, b, c) __builtin_amdgcn_mfma_f32_16x16x32_bf16((a), (b), (c), 0, 0, 0)

__device__ __forceinline__ short f2bs(float f) {
    unsigned u = __builtin_bit_cast(unsigned, f);
    unsigned r = (u + 0x7FFFu + ((u >> 16) & 1u)) >> 16;
    return (short)(unsigned short)r;
}

__device__ __forceinline__ float bs2f(short s) {
    unsigned u = ((unsigned)(unsigned short)s) << 16;
    return __builtin_bit_cast(float, u);
}

__device__ __forceinline__ void gload_lds16(const void* g, void* l) {
    __builtin_amdgcn_global_load_lds(
        (const __attribute__((address_space(1))) unsigned int*)g,
        (__attribute__((address_space(3))) unsigned int*)l, 16, 0, 0);
}

template <int N>
__device__ __forceinline__ void vmw() {
    if constexpr (N == 0) asm volatile("s_waitcnt vmcnt(0)" ::: "memory");
    else if constexpr (N == 3) asm volatile("s_waitcnt vmcnt(3)" ::: "memory");
    else if constexpr (N == 6) asm volatile("s_waitcnt vmcnt(6)" ::: "memory");
    else if constexpr (N == 8) asm volatile("s_waitcnt vmcnt(8)" ::: "memory");
    else if constexpr (N == 12) asm volatile("s_waitcnt vmcnt(12)" ::: "memory");
}

// ---------- fused: all six weight transposes fp32 (R x C) -> bf16 (C x R) ---
__global__ __launch_bounds__(256) void transpose_all_kernel(
    const float* __restrict__ wq, const float* __restrict__ wk,
    const float* __restrict__ wv, const float* __restrict__ wo,
    const float* __restrict__ w1, const float* __restrict__ w2,
    short* __restrict__ wqkvT, short* __restrict__ woT,
    short* __restrict__ w1T, short* __restrict__ w2T) {
    const int D = 2048;
    __shared__ float tile[32][33];
    int blk = blockIdx.x;
    const float* in;
    short* out;
    int R, C, bx, by;
    if (blk < 16384) {
        int r = blk >> 12;
        in = (r == 0) ? wq : (r == 1) ? wk : (r == 2) ? wv : wo;
        out = (r < 3) ? (wqkvT + (size_t)r * D * D) : woT;
        R = D; C = D;
        int lb = blk & 4095; bx = lb & 63; by = lb >> 6;
    } else if (blk < 32768) {
        in = w1; out = w1T; R = D; C = 4 * D;
        int lb = blk - 16384; bx = lb & 255; by = lb >> 8;
    } else {
        in = w2; out = w2T; R = 4 * D; C = D;
        int lb = blk - 32768; bx = lb & 63; by = lb >> 6;
    }
    const int tx = threadIdx.x & 31;
    const int ty = threadIdx.x >> 5;
    const int c0 = bx * 32, r0 = by * 32;
#pragma unroll
    for (int i = 0; i < 4; ++i) {
        int r = ty + i * 8;
        tile[r][tx] = in[(size_t)(r0 + r) * C + c0 + tx];
    }
    __syncthreads();
#pragma unroll
    for (int i = 0; i < 4; ++i) {
        int r = ty + i * 8;
        out[(size_t)(c0 + r) * R + r0 + tx] = f2bs(tile[tx][r]);
    }
}

// ---------- layernorm fp32 row (D=2048) -> bf16 row ----------
__global__ __launch_bounds__(256) void ln_kernel(const float* __restrict__ x,
                                                 const float* __restrict__ sc,
                                                 const float* __restrict__ sh,
                                                 short* __restrict__ out) {
    const int D = 2048;
    const int row = blockIdx.x;
    const int tid = threadIdx.x;
    __shared__ float red[4];
    const float4* xr = (const float4*)(x + (size_t)row * D);
    float4 v0 = xr[tid];
    float4 v1 = xr[tid + 256];
    float vals0[4] = {v0.x, v0.y, v0.z, v0.w};
    float vals1[4] = {v1.x, v1.y, v1.z, v1.w};

    float s = vals0[0] + vals0[1] + vals0[2] + vals0[3] + vals1[0] + vals1[1] + vals1[2] + vals1[3];
#pragma unroll
    for (int off = 32; off; off >>= 1) s += __shfl_xor(s, off);
    if ((tid & 63) == 0) red[tid >> 6] = s;
    __syncthreads();
    float mean = (red[0] + red[1] + red[2] + red[3]) * (1.0f / 2048.0f);
    __syncthreads();

    float q = 0.0f;
#pragma unroll
    for (int j = 0; j < 4; ++j) {
        float t0 = vals0[j] - mean;
        float t1 = vals1[j] - mean;
        q += t0 * t0 + t1 * t1;
    }
#pragma unroll
    for (int off = 32; off; off >>= 1) q += __shfl_xor(q, off);
    if ((tid & 63) == 0) red[tid >> 6] = q;
    __syncthreads();
    float var = (red[0] + red[1] + red[2] + red[3]) * (1.0f / 2048.0f);
    float inv = rsqrtf(var + 1e-5f);

    const int c0 = tid * 4;
    const int c1 = (tid + 256) * 4;
    short4v o0, o1;
#pragma unroll
    for (int j = 0; j < 4; ++j) {
        o0[j] = f2bs(sc[c0 + j] * ((vals0[j] - mean) * inv) + sh[c0 + j]);
        o1[j] = f2bs(sc[c1 + j] * ((vals1[j] - mean) * inv) + sh[c1 + j]);
    }
    *(short4v*)(out + (size_t)row * D + c0) = o0;
    *(short4v*)(out + (size_t)row * D + c1) = o1;
}

// ---------- layernorm bf16 row (D=2048) -> bf16 row ----------
__global__ __launch_bounds__(256) void ln_bf16_kernel(const short* __restrict__ x,
                                                      const float* __restrict__ sc,
                                                      const float* __restrict__ sh,
                                                      short* __restrict__ out) {
    const int D = 2048;
    const int row = blockIdx.x;
    const int tid = threadIdx.x;
    __shared__ float red[4];
    bf16x8 v = *(const bf16x8*)(x + (size_t)row * D + tid * 8);
    float vals[8];
#pragma unroll
    for (int j = 0; j < 8; ++j) vals[j] = bs2f(v[j]);

    float s = 0.f;
#pragma unroll
    for (int j = 0; j < 8; ++j) s += vals[j];
#pragma unroll
    for (int off = 32; off; off >>= 1) s += __shfl_xor(s, off);
    if ((tid & 63) == 0) red[tid >> 6] = s;
    __syncthreads();
    float mean = (red[0] + red[1] + red[2] + red[3]) * (1.0f / 2048.0f);
    __syncthreads();

    float q = 0.0f;
#pragma unroll
    for (int j = 0; j < 8; ++j) {
        float t = vals[j] - mean;
        q += t * t;
    }
#pragma unroll
    for (int off = 32; off; off >>= 1) q += __shfl_xor(q, off);
    if ((tid & 63) == 0) red[tid >> 6] = q;
    __syncthreads();
    float var = (red[0] + red[1] + red[2] + red[3]) * (1.0f / 2048.0f);
    float inv = rsqrtf(var + 1e-5f);

    const int c0 = tid * 8;
    bf16x8 o;
#pragma unroll
    for (int j = 0; j < 8; ++j)
        o[j] = f2bs(sc[c0 + j] * ((vals[j] - mean) * inv) + sh[c0 + j]);
    *(bf16x8*)(out + (size_t)row * D + c0) = o;
}

// ---------- gemm3d: 256x128, BK=64, 3-deep pipeline (qkv) ----------
// EPI 0: bf16  1: f32=acc+bias+f32res  2: bf16 gelu  3: bf16=acc+bias+f32res
// EPI 4: f32=acc+bias+bf16res
template <int EPI>
__global__ __launch_bounds__(512, 1) void gemm3d(const short* __restrict__ A,
                                                 const short* __restrict__ Bt,
                                                 int M, int N, int K,
                                                 void* __restrict__ Cout,
                                                 const float* __restrict__ bias,
                                                 const float* __restrict__ res,
                                                 float gconst) {
    extern __shared__ __align__(16) short lds[];  // 3 * 24576 shorts
    const int tid = threadIdx.x;
    const int lane = tid & 63;
    const int wid = tid >> 6;
    const int wm = wid >> 1, wn = wid & 1;
    const int l15 = lane & 15, grp = lane >> 4;

    const int gx = gridDim.x;
    int flat = (int)blockIdx.y * gx + (int)blockIdx.x;
    const int cpx = (gx * (int)gridDim.y) >> 3;
    flat = (flat & 7) * cpx + (flat >> 3);
    const int bx = flat % gx, by = flat / gx;
    const long m0 = (long)by * 256, n0 = (long)bx * 128;

    f32x4 zero = {0.f, 0.f, 0.f, 0.f};
    f32x4 acc[4][4];
#pragma unroll
    for (int i = 0; i < 4; i++)
#pragma unroll
        for (int j = 0; j < 4; j++) acc[i][j] = zero;

    auto STAGE = [&](long k0, int b) {
        short* bufA = lds + b * 24576;
        short* bufB = bufA + 16384;
#pragma unroll
        for (int j = 0; j < 4; ++j) {
            int c = tid + j * 512;
            int row = c >> 3, sl = (c & 7) ^ (row & 7);
            gload_lds16(A + (size_t)(m0 + row) * K + k0 + sl * 8,
                        bufA + (size_t)(wid * 64 + j * 512) * 8);
        }
#pragma unroll
        for (int j = 0; j < 2; ++j) {
            int c = tid + j * 512;
            int row = c >> 3, sl = (c & 7) ^ (row & 7);
            gload_lds16(Bt + (size_t)(n0 + row) * K + k0 + sl * 8,
                        bufB + (size_t)(wid * 64 + j * 512) * 8);
        }
    };

    const int nt = K >> 6;
    STAGE(0, 0);
    STAGE(64, 1);
    int cur = 0, nx2 = 2;

    for (int t = 0; t < nt; ++t) {
        if (t + 2 < nt) {
            STAGE((long)(t + 2) * 64, nx2);
            vmw<12>();
        } else if (t + 1 < nt) {
            vmw<6>();
        } else {
            vmw<0>();
        }
        __builtin_amdgcn_s_barrier();
        __builtin_amdgcn_sched_barrier(0);

        const short* bufA = lds + cur * 24576;
        const short* bufB = bufA + 16384;
        bf16x8 af[2][4], bfr[2][4];
#pragma unroll
        for (int kk = 0; kk < 2; ++kk) {
#pragma unroll
            for (int m = 0; m < 4; ++m) {
                int row = wm * 64 + m * 16 + l15;
                af[kk][m] = *(const bf16x8*)(bufA + row * 64 + (((kk * 4 + grp) ^ (row & 7)) * 8));
            }
#pragma unroll
            for (int n = 0; n < 4; ++n) {
                int row = wn * 64 + n * 16 + l15;
                bfr[kk][n] = *(const bf16x8*)(bufB + row * 64 + (((kk * 4 + grp) ^ (row & 7)) * 8));
            }
        }
        __builtin_amdgcn_s_setprio(1);
#pragma unroll
        for (int kk = 0; kk < 2; ++kk)
#pragma unroll
            for (int m = 0; m < 4; ++m)
#pragma unroll
                for (int n = 0; n < 4; ++n)
                    acc[m][n] = MFMA16x32(af[kk][m], bfr[kk][n], acc[m][n]);
        __builtin_amdgcn_s_setprio(0);
        asm volatile("s_waitcnt lgkmcnt(0)" ::: "memory");
        __builtin_amdgcn_s_barrier();
        __builtin_amdgcn_sched_barrier(0);
        cur = (cur == 2) ? 0 : cur + 1;
        nx2 = (nx2 == 2) ? 0 : nx2 + 1;
    }

#pragma unroll
    for (int m = 0; m < 4; m++) {
        long gr = m0 + wm * 64 + m * 16 + grp * 4;
#pragma unroll
        for (int n = 0; n < 4; n++) {
            long gcol = n0 + wn * 64 + n * 16 + l15;
#pragma unroll
            for (int r = 0; r < 4; r++) {
                float vv = acc[m][n][r];
                long idx = (gr + r) * N + gcol;
                if constexpr (EPI == 0) {
                    ((short*)Cout)[idx] = f2bs(vv);
                } else if constexpr (EPI == 1) {
                    ((float*)Cout)[idx] = vv + bias[gcol] + res[idx];
                } else if constexpr (EPI == 2) {
                    float t2 = vv + bias[gcol];
                    float g = 0.5f * t2 * (1.0f + gconst * (t2 + 0.044715f * t2 * t2 * t2));
                    ((short*)Cout)[idx] = f2bs(g);
                } else if constexpr (EPI == 3) {
                    ((short*)Cout)[idx] = f2bs(vv + bias[gcol] + res[idx]);
                } else {
                    ((float*)Cout)[idx] = vv + bias[gcol] + bs2f(((const short*)res)[idx]);
                }
            }
        }
    }
}

// ---------- gemm2c: 128x128, BK=64, 256 thr, 2-deep dbuf, 64KB -> 2 blk/CU --
// Wave tile 64x64 (wm=wid>>1, wn=wid&1), 32 MFMA + 16 ds_read/wave/K-tile.
template <int EPI>
__global__ __launch_bounds__(256, 2) void gemm2c(const short* __restrict__ A,
                                                 const short* __restrict__ Bt,
                                                 int M, int N, int K,
                                                 void* __restrict__ Cout,
                                                 const float* __restrict__ bias,
                                                 const float* __restrict__ res,
                                                 float gconst) {
    extern __shared__ __align__(16) short lds[];  // 2 * 16384 shorts = 64KB
    const int tid = threadIdx.x;
    const int lane = tid & 63;
    const int wid = tid >> 6;          // 0..3
    const int wm = wid >> 1, wn = wid & 1;
    const int l15 = lane & 15, grp = lane >> 4;

    const int gx = gridDim.x;
    int flat = (int)blockIdx.y * gx + (int)blockIdx.x;
    const int cpx = (gx * (int)gridDim.y) >> 3;
    flat = (flat & 7) * cpx + (flat >> 3);
    const int bx = flat % gx, by = flat / gx;
    const long m0 = (long)by * 128, n0 = (long)bx * 128;

    f32x4 zero = {0.f, 0.f, 0.f, 0.f};
    f32x4 acc[4][4];
#pragma unroll
    for (int i = 0; i < 4; i++)
#pragma unroll
        for (int j = 0; j < 4; j++) acc[i][j] = zero;

    auto STAGE = [&](int t, int b) {
        short* bufA = lds + b * 16384;
        short* bufB = bufA + 8192;
        const long k0 = (long)t << 6;
#pragma unroll
        for (int j = 0; j < 4; ++j) {
            int c = tid + j * 256;
            int row = c >> 3, sl = (c & 7) ^ (row & 7);
            gload_lds16(A + (size_t)(m0 + row) * K + k0 + sl * 8, bufA + (size_t)c * 8);
        }
#pragma unroll
        for (int j = 0; j < 4; ++j) {
            int c = tid + j * 256;
            int row = c >> 3, sl = (c & 7) ^ (row & 7);
            gload_lds16(Bt + (size_t)(n0 + row) * K + k0 + sl * 8, bufB + (size_t)c * 8);
        }
    };

    const int nt = K >> 6;
    STAGE(0, 0);
    STAGE(1, 1);

    for (int t = 0; t < nt; ++t) {
        if (t + 1 < nt) { vmw<8>(); } else { vmw<0>(); }
        __builtin_amdgcn_s_barrier();
        __builtin_amdgcn_sched_barrier(0);

        const short* bufA = lds + (t & 1) * 16384;
        const short* bufB = bufA + 8192;
        bf16x8 af[2][4], bfr[2][4];
#pragma unroll
        for (int kk = 0; kk < 2; ++kk) {
#pragma unroll
            for (int m = 0; m < 4; ++m) {
                int row = wm * 64 + m * 16 + l15;
                af[kk][m] = *(const bf16x8*)(bufA + row * 64 + (((kk * 4 + grp) ^ (row & 7)) * 8));
            }
#pragma unroll
            for (int n = 0; n < 4; ++n) {
                int row = wn * 64 + n * 16 + l15;
                bfr[kk][n] = *(const bf16x8*)(bufB + row * 64 + (((kk * 4 + grp) ^ (row & 7)) * 8));
            }
        }
        __builtin_amdgcn_s_setprio(1);
#pragma unroll
        for (int kk = 0; kk < 2; ++kk)
#pragma unroll
            for (int m = 0; m < 4; ++m)
#pragma unroll
                for (int n = 0; n < 4; ++n)
                    acc[m][n] = MFMA16x32(af[kk][m], bfr[kk][n], acc[m][n]);
        __builtin_amdgcn_s_setprio(0);
        asm volatile("s_waitcnt lgkmcnt(0)" ::: "memory");
        __builtin_amdgcn_s_barrier();
        __builtin_amdgcn_sched_barrier(0);
        if (t + 2 < nt) STAGE(t + 2, t & 1);
    }

#pragma unroll
    for (int m = 0; m < 4; m++) {
        long gr = m0 + wm * 64 + m * 16 + grp * 4;
#pragma unroll
        for (int n = 0; n < 4; n++) {
            long gcol = n0 + wn * 64 + n * 16 + l15;
#pragma unroll
            for (int r = 0; r < 4; r++) {
                float vv = acc[m][n][r];
                long idx = (gr + r) * N + gcol;
                if constexpr (EPI == 3) {
                    ((short*)Cout)[idx] = f2bs(vv + bias[gcol] + res[idx]);
                } else if constexpr (EPI == 4) {
                    ((float*)Cout)[idx] = vv + bias[gcol] + bs2f(((const short*)res)[idx]);
                } else {
                    ((short*)Cout)[idx] = f2bs(vv);
                }
            }
        }
    }
}

// ---------- gemm3b: 256x128, BK=32, 3-deep, 72KB LDS (ffn1) ----------
template <int EPI>
__global__ __launch_bounds__(512, 4) void gemm3b(const short* __restrict__ A,
                                                 const short* __restrict__ Bt,
                                                 int M, int N, int K,
                                                 void* __restrict__ Cout,
                                                 const float* __restrict__ bias,
                                                 const float* __restrict__ res,
                                                 float gconst) {
    extern __shared__ __align__(16) short lds[];  // 3 * 12288 shorts = 72KB
    const int tid = threadIdx.x;
    const int lane = tid & 63;
    const int wid = tid >> 6;
    const int wm = wid >> 1, wn = wid & 1;
    const int l15 = lane & 15, grp = lane >> 4;

    const int gx = gridDim.x;
    int flat = (int)blockIdx.y * gx + (int)blockIdx.x;
    const int cpx = (gx * (int)gridDim.y) >> 3;
    flat = (flat & 7) * cpx + (flat >> 3);
    const int bx = flat % gx, by = flat / gx;
    const long m0 = (long)by * 256, n0 = (long)bx * 128;

    f32x4 zero = {0.f, 0.f, 0.f, 0.f};
    f32x4 acc[4][4];
#pragma unroll
    for (int i = 0; i < 4; i++)
#pragma unroll
        for (int j = 0; j < 4; j++) acc[i][j] = zero;

    auto STAGE = [&](int t, int b) {
        short* bufA = lds + b * 12288;
        short* bufB = bufA + 8192;
        const long k0 = (long)t << 5;
#pragma unroll
        for (int j = 0; j < 2; ++j) {
            int c = tid + j * 512;
            int row = c >> 2, sl = (c & 3) ^ ((row ^ (row >> 2)) & 3);
            gload_lds16(A + (size_t)(m0 + row) * K + k0 + sl * 8, bufA + (size_t)c * 8);
        }
        {
            int c = tid;
            int row = c >> 2, sl = (c & 3) ^ ((row ^ (row >> 2)) & 3);
            gload_lds16(Bt + (size_t)(n0 + row) * K + k0 + sl * 8, bufB + (size_t)c * 8);
        }
    };

    const int nt = K >> 5;
    STAGE(0, 0);
    STAGE(1, 1);
    int cur = 0, nx2 = 2;

    for (int t = 0; t < nt; ++t) {
        if (t + 2 < nt) {
            STAGE(t + 2, nx2);
            vmw<6>();
        } else if (t + 1 < nt) {
            vmw<3>();
        } else {
            vmw<0>();
        }
        __builtin_amdgcn_s_barrier();
        __builtin_amdgcn_sched_barrier(0);

        const short* bufA = lds + cur * 12288;
        const short* bufB = bufA + 8192;
        bf16x8 af[4], bfr[4];
#pragma unroll
        for (int m = 0; m < 4; ++m) {
            int row = wm * 64 + m * 16 + l15;
            af[m] = *(const bf16x8*)(bufA + row * 32 + (((grp ^ (row ^ (row >> 2))) & 3) * 8));
        }
#pragma unroll
        for (int n = 0; n < 4; ++n) {
            int row = wn * 64 + n * 16 + l15;
            bfr[n] = *(const bf16x8*)(bufB + row * 32 + (((grp ^ (row ^ (row >> 2))) & 3) * 8));
        }
        __builtin_amdgcn_s_setprio(1);
#pragma unroll
        for (int m = 0; m < 4; ++m)
#pragma unroll
            for (int n = 0; n < 4; ++n)
                acc[m][n] = MFMA16x32(af[m], bfr[n], acc[m][n]);
        __builtin_amdgcn_s_setprio(0);
        asm volatile("s_waitcnt lgkmcnt(0)" ::: "memory");
        __builtin_amdgcn_s_barrier();
        __builtin_amdgcn_sched_barrier(0);
        cur = (cur == 2) ? 0 : cur + 1;
        nx2 = (nx2 == 2) ? 0 : nx2 + 1;
    }

#pragma unroll
    for (int m = 0; m < 4; m++) {
        long gr = m0 + wm * 64 + m * 16 + grp * 4;
#pragma unroll
        for (int n = 0; n < 4; n++) {
            long gcol = n0 + wn * 64 + n * 16 + l15;
#pragma unroll
            for (int r = 0; r < 4; r++) {
                float vv = acc[m][n][r];
                long idx = (gr + r) * N + gcol;
                if constexpr (EPI == 0) {
                    ((short*)Cout)[idx] = f2bs(vv);
                } else if constexpr (EPI == 2) {
                    float t2 = vv + bias[gcol];
                    float g = 0.5f * t2 * (1.0f + gconst * (t2 + 0.044715f * t2 * t2 * t2));
                    ((short*)Cout)[idx] = f2bs(g);
                } else {
                    ((float*)Cout)[idx] = vv + bias[gcol] + res[idx];
                }
            }
        }
    }
}

// ---------- reshape: qkv V-cols -> Vt[32][128][2048] (transposed) ----------
__global__ __launch_bounds__(256) void reshape_v_kernel(const short* __restrict__ qkv,
                                                        short* __restrict__ Vt) {
    __shared__ short tile[32][33];
    const int bid = blockIdx.x;
    const int dt = bid & 3, st = (bid >> 2) & 63, bh = bid >> 8;
    const int b = bh >> 4, h = bh & 15;
    const int s0 = st * 32, d0 = dt * 32;
    const int tx = threadIdx.x & 31, ty = threadIdx.x >> 5;
#pragma unroll
    for (int i = 0; i < 4; ++i) {
        int s = ty + i * 8;
        tile[s][tx] = qkv[(size_t)(b * 2048 + s0 + s) * 6144 + 4096 + h * 128 + d0 + tx];
    }
    __syncthreads();
#pragma unroll
    for (int i = 0; i < 4; ++i) {
        int d = ty + i * 8;
        Vt[((size_t)bh * 128 + d0 + d) * 2048 + s0 + tx] = tile[tx][d];
    }
}

// ---------- causal flash attention, paired q-tiles + double-buffered K/V ----
__global__ __launch_bounds__(256) void flash3_kernel(const short* __restrict__ qp,  // qkv, ld 6144
                                                     const short* __restrict__ Vt,
                                                     short* __restrict__ ctx) {
    const int S = 2048, D = 2048, HD = 128, LD = 6144;
    __shared__ __align__(16) short Ks[2][64 * 128];
    __shared__ __align__(16) short Vs[2][64 * 128];
    __shared__ __align__(16) short Ps[4][16 * 64];
    const int tid = threadIdx.x;
    const int lane = tid & 63, wid = tid >> 6;
    const int l15 = lane & 15, grp = lane >> 4;

    int bid = (int)blockIdx.x;
    bid = (bid & 7) * 64 + (bid >> 3);
    const int p = bid & 15, bh = bid >> 4;
    const int b = bh >> 4, h = bh & 15;
    const int qtH = 31 - p;
    const int nH = qtH + 1;
    const float scale = 0.08838834764831845f;
    const float NEGINF = -__builtin_inff();

    const short* Kbase = qp + (size_t)b * S * LD + 2048 + (size_t)h * HD;
    const short* Vbase = Vt + (size_t)bh * 128 * S;
    short* Psw = &Ps[wid][0];

    f32x4 zero = {0.f, 0.f, 0.f, 0.f};
    bf16x8 aq[4];
    float m_[4], l_[4];
    f32x4 o[8];

    int qt = qtH;
    int qw = qt * 64 + wid * 16;
    {
        const short* qrow = qp + (size_t)(b * S + qw + l15) * LD + h * HD;
#pragma unroll
        for (int kc = 0; kc < 4; kc++) aq[kc] = *(const bf16x8*)(qrow + kc * 32 + grp * 8);
    }
#pragma unroll
    for (int r = 0; r < 4; r++) { m_[r] = NEGINF; l_[r] = 0.f; }
#pragma unroll
    for (int n = 0; n < 8; n++) o[n] = zero;

#pragma unroll
    for (int j = 0; j < 4; ++j) {
        int c = tid + j * 256;
        int r = c >> 4, sl = c & 15;
        gload_lds16(Kbase + (size_t)r * LD + ((sl ^ (r & 7)) * 8),
                    Ks[0] + (size_t)(wid * 64 + j * 256) * 8);
    }
#pragma unroll
    for (int j = 0; j < 4; ++j) {
        int c = tid + j * 256;
        int d = c >> 3, sl = c & 7;
        gload_lds16(Vbase + (size_t)d * S + ((sl ^ (d & 7)) * 8),
                    Vs[0] + (size_t)(wid * 64 + j * 256) * 8);
    }
    __syncthreads();

    int cur = 0;
    for (int i = 0; i < 33; ++i) {
        const int kt = (i < nH) ? i : (i - nH);
        const bool lastT = (kt == qt);

        if (i + 1 < 33) {
            const int ktn = (i + 1 < nH) ? (i + 1) : (i + 1 - nH);
            const long kn0 = (long)ktn * 64;
            const short* Kg = Kbase + (size_t)kn0 * LD;
            const short* Vg = Vbase + kn0;
            short* kd = Ks[cur ^ 1];
            short* vd = Vs[cur ^ 1];
#pragma unroll
            for (int j = 0; j < 4; ++j) {
                int c = tid + j * 256;
                int r = c >> 4, sl = c & 15;
                gload_lds16(Kg + (size_t)r * LD + ((sl ^ (r & 7)) * 8),
                            kd + (size_t)(wid * 64 + j * 256) * 8);
            }
#pragma unroll
            for (int j = 0; j < 4; ++j) {
                int c = tid + j * 256;
                int d = c >> 3, sl = c & 7;
                gload_lds16(Vg + (size_t)d * S + ((sl ^ (d & 7)) * 8),
                            vd + (size_t)(wid * 64 + j * 256) * 8);
            }
        }

        const short* Kc = Ks[cur];
        const short* Vc = Vs[cur];

        f32x4 s[4] = {zero, zero, zero, zero};
#pragma unroll
        for (int n = 0; n < 4; ++n) {
            int r = n * 16 + l15;
#pragma unroll
            for (int kc = 0; kc < 4; ++kc) {
                bf16x8 kb = *(const bf16x8*)(Kc + r * 128 + (((kc * 4 + grp) ^ (r & 7)) * 8));
                s[n] = MFMA16x32(aq[kc], kb, s[n]);
            }
        }

        float al[4];
#pragma unroll
        for (int r = 0; r < 4; ++r) {
            float v[4];
#pragma unroll
            for (int n = 0; n < 4; ++n) v[n] = s[n][r] * scale;
            if (lastT) {
                int qrel = wid * 16 + grp * 4 + r;
#pragma unroll
                for (int n = 0; n < 4; ++n)
                    if (n * 16 + l15 > qrel) v[n] = NEGINF;
            }
            float mx = fmaxf(fmaxf(v[0], v[1]), fmaxf(v[2], v[3]));
            mx = fmaxf(mx, __shfl_xor(mx, 1));
            mx = fmaxf(mx, __shfl_xor(mx, 2));
            mx = fmaxf(mx, __shfl_xor(mx, 4));
            mx = fmaxf(mx, __shfl_xor(mx, 8));
            float mn = fmaxf(m_[r], mx);
            float sc_ = __expf(m_[r] - mn);
            float rs = 0.f;
            int q = grp * 4 + r;
#pragma unroll
            for (int n = 0; n < 4; ++n) {
                v[n] = __expf(v[n] - mn);
                rs += v[n];
                Psw[q * 64 + (((n * 2 + (l15 >> 3)) ^ (q & 7)) * 8) + (l15 & 7)] = f2bs(v[n]);
            }
            rs += __shfl_xor(rs, 1);
            rs += __shfl_xor(rs, 2);
            rs += __shfl_xor(rs, 4);
            rs += __shfl_xor(rs, 8);
            l_[r] = l_[r] * sc_ + rs;
            m_[r] = mn;
            al[r] = sc_;
        }
#pragma unroll
        for (int n = 0; n < 8; n++) {
            f32x4 t = o[n];
            t[0] *= al[0]; t[1] *= al[1]; t[2] *= al[2]; t[3] *= al[3];
            o[n] = t;
        }

        bf16x8 pa[2];
#pragma unroll
        for (int kc = 0; kc < 2; ++kc)
            pa[kc] = *(const bf16x8*)(Psw + l15 * 64 + (((kc * 4 + grp) ^ (l15 & 7)) * 8));
#pragma unroll
        for (int n = 0; n < 8; ++n) {
            int d = n * 16 + l15;
#pragma unroll
            for (int kc = 0; kc < 2; ++kc) {
                bf16x8 vb = *(const bf16x8*)(Vc + d * 64 + (((kc * 4 + grp) ^ (d & 7)) * 8));
                o[n] = MFMA16x32(pa[kc], vb, o[n]);
            }
        }

        if (lastT) {
            float inv[4];
#pragma unroll
            for (int r = 0; r < 4; ++r) inv[r] = 1.0f / l_[r];
            short* cb_ = ctx + (size_t)(b * S + qw + grp * 4) * D + h * HD + l15;
#pragma unroll
            for (int n = 0; n < 8; ++n)
#pragma unroll
                for (int r = 0; r < 4; ++r)
                    cb_[(size_t)r * D + n * 16] = f2bs(o[n][r] * inv[r]);
            if (i < 32) {
                qt = 31 - qtH;
                qw = qt * 64 + wid * 16;
                const short* qrow = qp + (size_t)(b * S + qw + l15) * LD + h * HD;
#pragma unroll
                for (int kc = 0; kc < 4; kc++) aq[kc] = *(const bf16x8*)(qrow + kc * 32 + grp * 8);
#pragma unroll
                for (int r = 0; r < 4; r++) { m_[r] = NEGINF; l_[r] = 0.f; }
#pragma unroll
                for (int n = 0; n < 8; n++) o[n] = zero;
            }
        }
        __syncthreads();
        cur ^= 1;
    }
}

// ---------------------------------------------------------------------------
extern "C" void kernel_launch(void* const* d_in, const int* in_sizes, int n_in,
                              void* d_out, int out_size, void* d_ws, size_t ws_size,
                              hipStream_t stream) {
    const float* x    = (const float*)d_in[0];
    const float* wq   = (const float*)d_in[1];
    const float* wk   = (const float*)d_in[2];
    const float* wv   = (const float*)d_in[3];
    const float* wo   = (const float*)d_in[4];
    const float* bo   = (const float*)d_in[5];
    const float* w1   = (const float*)d_in[6];
    const float* b1   = (const float*)d_in[7];
    const float* w2   = (const float*)d_in[8];
    const float* b2   = (const float*)d_in[9];
    const float* lnsc = (const float*)d_in[10];
    const float* lnsh = (const float*)d_in[11];

    const int B = 2, S = 2048, D = 2048;
    const int M = B * S;  // 4096
    const int LDS_3D = 3 * 24576 * 2;   // 147456 (gemm3d)
    const int LDS_3B = 3 * 12288 * 2;   // 73728  (gemm3b)
    const int LDS_2C = 2 * 16384 * 2;   // 65536  (gemm2c)

    char* p = (char*)d_ws;
    short* wqkvT = (short*)p; p += (size_t)3 * D * D * 2;
    short* woT   = (short*)p; p += (size_t)D * D * 2;
    short* w1T   = (short*)p; p += (size_t)4 * D * D * 2;
    short* w2T   = (short*)p; p += (size_t)4 * D * D * 2;
    short* lnb   = (short*)p; p += (size_t)M * D * 2;
    short* qkvb  = (short*)p;
    short* h1    = qkvb;                                    // reuse qkv+ctx span
    p += (size_t)M * 3 * D * 2;
    short* ctxb  = (short*)p; p += (size_t)M * D * 2;
    short* x2    = (short*)p; p += (size_t)M * D * 2;       // bf16 residual stream

    short* Vt = x2;             // overlays x2 (proj writes x2 only after flash)

    const float gconst = tanhf(sqrtf(2.0f / 3.14159265358979323846f));

    hipFuncSetAttribute((const void*)&gemm3d<0>, hipFuncAttributeMaxDynamicSharedMemorySize, LDS_3D);
    hipFuncSetAttribute((const void*)&gemm3b<2>, hipFuncAttributeMaxDynamicSharedMemorySize, LDS_3B);
    hipFuncSetAttribute((const void*)&gemm2c<3>, hipFuncAttributeMaxDynamicSharedMemorySize, LDS_2C);
    hipFuncSetAttribute((const void*)&gemm2c<4>, hipFuncAttributeMaxDynamicSharedMemorySize, LDS_2C);

    dim3 blk(256);
    transpose_all_kernel<<<dim3(49152), blk, 0, stream>>>(
        wq, wk, wv, wo, w1, w2, wqkvT, woT, w1T, w2T);

    ln_kernel<<<dim3(M), blk, 0, stream>>>(x, lnsc, lnsh, lnb);
    // qkv: gemm3d 256x128 -> grid 48x16 = 768 blocks
    gemm3d<0><<<dim3(3 * D / 128, M / 256), dim3(512), LDS_3D, stream>>>(
        lnb, wqkvT, M, 3 * D, D, qkvb, nullptr, nullptr, 0.f);

    reshape_v_kernel<<<dim3(8192), blk, 0, stream>>>(qkvb, Vt);

    flash3_kernel<<<dim3(512), blk, 0, stream>>>(qkvb, Vt, ctxb);

    // proj: gemm2c 128x128, 2 blocks/CU -> grid 16x32 = 512 (one round)
    gemm2c<3><<<dim3(D / 128, M / 128), blk, LDS_2C, stream>>>(
        ctxb, woT, M, D, D, x2, bo, x, 0.f);
    ln_bf16_kernel<<<dim3(M), blk, 0, stream>>>(x2, lnsc, lnsh, lnb);
    // ffn1: gemm3b 256x128 BK=32 -> grid 64x16 = 1024
    gemm3b<2><<<dim3(4 * D / 128, M / 256), dim3(512), LDS_3B, stream>>>(
        lnb, w1T, M, 4 * D, D, h1, b1, nullptr, gconst);
    // ffn2: gemm2c 128x128, 2 blocks/CU -> grid 16x32 = 512 (one round)
    gemm2c<4><<<dim3(D / 128, M / 128), blk, LDS_2C, stream>>>(
        h1, w2T, M, D, 4 * D, (float*)d_out, b2, (const float*)x2, 0.f);
}